// Round 4
// baseline (227.934 us; speedup 1.0000x reference)
//
#include <hip/hip_runtime.h>
#include <hip/hip_bf16.h>
#include <stdint.h>

// Problem: B=2, S=2048, F=2048, H=16, DH=128, causal, ROPE_BASE=1e4, fp32 I/O.
#define NB 2
#define NS 2048
#define NFE 2048
#define NH 16
#define NDH 128

// softmax scale folded into q (log2 domain): 1/sqrt(128) * log2(e)
#define QSCALE (0.08838834764831845f * 1.4426950408889634f)

typedef __attribute__((ext_vector_type(4))) float f32x4;
typedef __attribute__((ext_vector_type(8))) __bf16 bf16x8;

__device__ __forceinline__ uint16_t f2bf(float f) {
  uint32_t u = __builtin_bit_cast(uint32_t, f);
  return (uint16_t)((u + 0x7fffu + ((u >> 16) & 1u)) >> 16);
}

__device__ __forceinline__ void gload_lds16(const void* g, void* l) {
  __builtin_amdgcn_global_load_lds((const __attribute__((address_space(1))) void*)g,
                                   (__attribute__((address_space(3))) void*)l,
                                   16, 0, 0);
}

#define MFMA16(a, b, c) __builtin_amdgcn_mfma_f32_16x16x32_bf16(a, b, c, 0, 0, 0)

// ---------------- kernel 0a: fp32 -> bf16 convert (in_q) ----------------
__global__ void k_convert(const float* __restrict__ x, uint16_t* __restrict__ y) {
  int i = (blockIdx.x * 256 + threadIdx.x) * 4;
  float4 v = *(const float4*)(x + i);
  ushort4 o;
  o.x = f2bf(v.x); o.y = f2bf(v.y); o.z = f2bf(v.z); o.w = f2bf(v.w);
  *(ushort4*)(y + i) = o;
}

// ---------------- kernel 0b: W transpose+convert: [K][N] f32 -> [N][K] bf16 ---
__global__ void k_wt(const float* __restrict__ Wq, const float* __restrict__ Wk,
                     const float* __restrict__ Wv, uint16_t* __restrict__ Wt) {
  int which = blockIdx.z;
  const float* Wsrc = (which == 0) ? Wq : ((which == 1) ? Wk : Wv);
  int k0 = blockIdx.x * 64, n0 = blockIdx.y * 64;
  __shared__ uint16_t tile[64][65];
  int t = threadIdx.x;
#pragma unroll
  for (int it = 0; it < 4; ++it) {
    int vec = t + it * 256;        // 0..1023
    int r = vec >> 4, c4 = vec & 15;
    float4 v = *(const float4*)&Wsrc[(size_t)(k0 + r) * NFE + n0 + c4 * 4];
    tile[r][c4 * 4 + 0] = f2bf(v.x);
    tile[r][c4 * 4 + 1] = f2bf(v.y);
    tile[r][c4 * 4 + 2] = f2bf(v.z);
    tile[r][c4 * 4 + 3] = f2bf(v.w);
  }
  __syncthreads();
#pragma unroll
  for (int it = 0; it < 4; ++it) {
    int vec = t + it * 256;
    int r = vec >> 4, c4 = vec & 15;   // r = n row, c4*4 = k offset
    ushort4 o;
    o.x = tile[c4 * 4 + 0][r];
    o.y = tile[c4 * 4 + 1][r];
    o.z = tile[c4 * 4 + 2][r];
    o.w = tile[c4 * 4 + 3][r];
    *(ushort4*)&Wt[(size_t)which * NFE * NFE + (size_t)(n0 + r) * NFE + k0 + c4 * 4] = o;
  }
}

// ---------------- kernel 0c: RoPE cos/sin tables [S][64] fp32 ----------------
__global__ void k_rope_tab(float* __restrict__ cosT, float* __restrict__ sinT,
                           const int* __restrict__ offp) {
  int tid = blockIdx.x * 256 + threadIdx.x;   // 0..131071
  int s = tid >> 6, i = tid & 63;
  float off = (float)offp[0];
  float inv = expf(-((float)i / 64.0f) * logf(10000.0f));
  float ang = ((float)s + off) * inv;
  cosT[tid] = cosf(ang);
  sinT[tid] = sinf(ang);
}

// ---------------- kernel 1: QKV GEMM (256x256 8-phase) + bias + RoPE ----------------
// A: [4096][2048] bf16; Wt: [6144][2048] bf16 (n-major).  Grid 384 (16 x 24).
// 512 thr / 8 waves (4M x 2N): wave = 64 rows x 128 cols = one full head (RoPE local).
// BK=64, double-buffered 128 KiB LDS, counted vmcnt (4@p3, 8@p7), raw barriers only.
__global__ __launch_bounds__(512, 2) void k_gemm_qkv(
    const uint16_t* __restrict__ A, const uint16_t* __restrict__ Wt,
    const float* __restrict__ bq, const float* __restrict__ bk, const float* __restrict__ bv,
    const float* __restrict__ cosT, const float* __restrict__ sinT,
    uint16_t* __restrict__ qws, uint16_t* __restrict__ kws, uint16_t* __restrict__ vws) {
  __shared__ uint16_t SMEM[4][16384];   // [buf*2 + (0=A,1=B)][256*64], 128 KiB

  int bid = blockIdx.x;
  int swzb = (bid & 7) * 48 + (bid >> 3);    // bijective: 384 % 8 == 0
  int bx = swzb & 15, by = swzb >> 4;        // bx: M-tile 0..15, by: N-tile 0..23
  int t = threadIdx.x, l = t & 63, w = t >> 6;
  int g = l >> 4, c = l & 15;
  int wr = w >> 1, wc = w & 1;

  // staging geometry: chunk q = it*512 + t; row-in-half = it*64 + (t>>3); sub = t&7
  int row0 = t >> 3;
  int swz = ((t & 7) ^ (row0 & 7)) << 3;     // pre-swizzled source column (elements)
  const uint16_t* aTh = A + ((size_t)bx * 256 + row0) * NFE + swz;
  const uint16_t* bTh = Wt + ((size_t)by * 256 + row0) * NFE + swz;

#define STG(sbase, slot, h, kt)                                                   \
  do {                                                                            \
    const uint16_t* _s = (sbase) + (size_t)((h) * 128) * NFE + (size_t)(kt) * 64; \
    char* _d = (char*)(&SMEM[slot][0]) + (h) * 16384 + t * 16;                    \
    gload_lds16(_s, _d);                                                          \
    gload_lds16(_s + (size_t)64 * NFE, _d + 8192);                                \
  } while (0)

#define LDA_(buf, mh)                                                             \
  _Pragma("unroll") for (int mi = 0; mi < 2; ++mi)                                \
  _Pragma("unroll") for (int kk = 0; kk < 2; ++kk) {                              \
    int row = wr * 64 + ((mh) * 2 + mi) * 16 + c;                                 \
    af[mi][kk] = *(const bf16x8*)((const char*)SMEM[(buf) * 2] + row * 128 +      \
                                  (((kk * 4 + g) ^ (row & 7)) << 4));             \
  }

#define LDB_(buf, nh, BF)                                                         \
  _Pragma("unroll") for (int ni = 0; ni < 4; ++ni)                                \
  _Pragma("unroll") for (int kk = 0; kk < 2; ++kk) {                              \
    int row = wc * 128 + ((nh) * 4 + ni) * 16 + c;                                \
    BF[ni][kk] = *(const bf16x8*)((const char*)SMEM[(buf) * 2 + 1] + row * 128 +  \
                                  (((kk * 4 + g) ^ (row & 7)) << 4));             \
  }

#define MM_(mh, nh, BF)                                                           \
  _Pragma("unroll") for (int kk = 0; kk < 2; ++kk)                                \
  _Pragma("unroll") for (int mi = 0; mi < 2; ++mi)                                \
  _Pragma("unroll") for (int ni = 0; ni < 4; ++ni)                                \
    acc[(mh) * 2 + mi][(nh) * 4 + ni] =                                           \
        MFMA16(af[mi][kk], BF[ni][kk], acc[(mh) * 2 + mi][(nh) * 4 + ni]);

#define BAR_MID()                                          \
  do {                                                     \
    __builtin_amdgcn_s_barrier();                          \
    asm volatile("s_waitcnt lgkmcnt(0)" ::: "memory");     \
    __builtin_amdgcn_sched_barrier(0);                     \
    __builtin_amdgcn_s_setprio(1);                         \
  } while (0)
#define BAR_END()                                          \
  do {                                                     \
    __builtin_amdgcn_s_setprio(0);                         \
    __builtin_amdgcn_s_barrier();                          \
  } while (0)

  f32x4 acc[4][8];
#pragma unroll
  for (int m = 0; m < 4; ++m)
#pragma unroll
    for (int n = 0; n < 8; ++n) acc[m][n] = (f32x4){0.f, 0.f, 0.f, 0.f};

  bf16x8 af[2][2], bflo[4][2], bfhi[4][2];

  // prologue: stage T0 (buf0) then T1 (buf1); FIFO order matters.
  STG(aTh, 0, 0, 0); STG(aTh, 0, 1, 0); STG(bTh, 1, 0, 0); STG(bTh, 1, 1, 0);
  STG(aTh, 2, 0, 1); STG(aTh, 2, 1, 1); STG(bTh, 3, 0, 1); STG(bTh, 3, 1, 1);
  asm volatile("s_waitcnt vmcnt(8)" ::: "memory");   // T0 resident
  __builtin_amdgcn_s_barrier();

  // main loop: 15 full iterations (tiles 2i, 2i+1), staging tiles 2i+2, 2i+3
  for (int i = 0; i < 15; ++i) {
    int t2 = 2 * i + 2, t3 = 2 * i + 3;
    // ---- buf0 = tile 2i ----
    // p0
    LDA_(0, 0); LDB_(0, 0, bflo);
    BAR_MID(); MM_(0, 0, bflo); BAR_END();
    // p1
    LDB_(0, 1, bfhi);
    BAR_MID(); MM_(0, 1, bfhi); BAR_END();
    // p2  (buf0.B dead after p1 -> stage T2.B0)
    LDA_(0, 1);
    STG(bTh, 1, 0, t2);
    BAR_MID(); MM_(1, 1, bfhi); BAR_END();
    // p3  (stage T2.B1; gate: T1 must be resident for p4)
    STG(bTh, 1, 1, t2);
    asm volatile("s_waitcnt vmcnt(4)" ::: "memory");
    BAR_MID(); MM_(1, 0, bflo); BAR_END();
    // ---- buf1 = tile 2i+1 ----
    // p4  (buf0.A dead after p2 -> stage T2.A0)
    LDA_(1, 0); LDB_(1, 0, bflo);
    STG(aTh, 0, 0, t2);
    BAR_MID(); MM_(0, 0, bflo); BAR_END();
    // p5  (stage T2.A1)
    LDB_(1, 1, bfhi);
    STG(aTh, 0, 1, t2);
    BAR_MID(); MM_(0, 1, bfhi); BAR_END();
    // p6  (buf1.B dead after p5 -> stage T3.B0)
    LDA_(1, 1);
    STG(bTh, 3, 0, t3);
    BAR_MID(); MM_(1, 1, bfhi); BAR_END();
    // p7  (stage T3.B1, T3.A0, T3.A1; gate: T2 resident for next p0)
    STG(bTh, 3, 1, t3);
    STG(aTh, 2, 0, t3);
    STG(aTh, 2, 1, t3);
    asm volatile("s_waitcnt vmcnt(8)" ::: "memory");
    BAR_MID(); MM_(1, 0, bflo); BAR_END();
  }

  // peeled last iteration: tiles 30 (buf0), 31 (buf1); no staging
  {
    LDA_(0, 0); LDB_(0, 0, bflo);
    BAR_MID(); MM_(0, 0, bflo); BAR_END();
    LDB_(0, 1, bfhi);
    BAR_MID(); MM_(0, 1, bfhi); BAR_END();
    LDA_(0, 1);
    BAR_MID(); MM_(1, 1, bfhi); BAR_END();
    asm volatile("s_waitcnt vmcnt(0)" ::: "memory");   // T31 resident
    BAR_MID(); MM_(1, 0, bflo); BAR_END();
    LDA_(1, 0); LDB_(1, 0, bflo);
    BAR_MID(); MM_(0, 0, bflo); BAR_END();
    LDB_(1, 1, bfhi);
    BAR_MID(); MM_(0, 1, bfhi); BAR_END();
    LDA_(1, 1);
    BAR_MID(); MM_(1, 1, bfhi); BAR_END();
    BAR_MID(); MM_(1, 0, bflo); BAR_END();
  }

  // epilogue: wave owns rows [bx*256+wr*64, +64), head ghead = by*2 + wc
  int ghead = by * 2 + wc;
  int which = ghead >> 4, h = ghead & 15;
  const float* bias = (which == 0) ? bq : ((which == 1) ? bk : bv);
  uint16_t* outp = (which == 0) ? qws : ((which == 1) ? kws : vws);
  float scl = (which == 0) ? QSCALE : 1.0f;
  int mbase = bx * 256 + wr * 64;
  if (which < 2) {
#pragma unroll
    for (int m = 0; m < 4; ++m)
#pragma unroll
      for (int nf = 0; nf < 4; ++nf) {
        int i2 = nf * 16 + c;   // rotary index 0..63
        float b1 = bias[h * NDH + i2], b2 = bias[h * NDH + 64 + i2];
#pragma unroll
        for (int j = 0; j < 4; ++j) {
          int r = mbase + m * 16 + g * 4 + j;
          int bb = r >> 11, s = r & (NS - 1);
          float cs = cosT[(s << 6) + i2], sn = sinT[(s << 6) + i2];
          float x1 = acc[m][nf][j] + b1;
          float x2 = acc[m][nf + 4][j] + b2;
          uint16_t* op = outp + ((size_t)(bb * NH + h) * NS + s) * NDH;
          op[i2] = f2bf((x1 * cs - x2 * sn) * scl);
          op[64 + i2] = f2bf((x1 * sn + x2 * cs) * scl);
        }
      }
  } else {
#pragma unroll
    for (int m = 0; m < 4; ++m)
#pragma unroll
      for (int nf = 0; nf < 8; ++nf) {
        int d = nf * 16 + c;
        float bv_ = bias[h * NDH + d];
#pragma unroll
        for (int j = 0; j < 4; ++j) {
          int r = mbase + m * 16 + g * 4 + j;
          int bb = r >> 11, s = r & (NS - 1);
          outp[((size_t)(bb * NH + h) * NS + s) * NDH + d] = f2bf(acc[m][nf][j] + bv_);
        }
      }
  }
#undef STG
#undef LDA_
#undef LDB_
#undef MM_
#undef BAR_MID
#undef BAR_END
}

// ---------------- kernel 1.5: V transpose [bh][s][d] -> [bh][d][s] ----------------
__global__ void k_vt(const uint16_t* __restrict__ v, uint16_t* __restrict__ vt) {
  int bh = blockIdx.z;
  int s0 = blockIdx.x * 64, d0 = blockIdx.y * 64;
  __shared__ uint16_t tile[64][65];
  int t = threadIdx.x;
#pragma unroll
  for (int it = 0; it < 4; ++it) {
    int vec = t + it * 256;
    int r = vec >> 4, c4 = vec & 15;     // r = s row, c4*4 = d offset
    ushort4 x = *(const ushort4*)&v[((size_t)bh * NS + s0 + r) * NDH + d0 + c4 * 4];
    tile[r][c4 * 4 + 0] = x.x;
    tile[r][c4 * 4 + 1] = x.y;
    tile[r][c4 * 4 + 2] = x.z;
    tile[r][c4 * 4 + 3] = x.w;
  }
  __syncthreads();
#pragma unroll
  for (int it = 0; it < 4; ++it) {
    int vec = t + it * 256;
    int r = vec >> 4, c4 = vec & 15;     // r = d row, c4*4 = s offset
    ushort4 o;
    o.x = tile[c4 * 4 + 0][r];
    o.y = tile[c4 * 4 + 1][r];
    o.z = tile[c4 * 4 + 2][r];
    o.w = tile[c4 * 4 + 3][r];
    *(ushort4*)&vt[((size_t)bh * NDH + d0 + r) * NS + s0 + c4 * 4] = o;
  }
}

// ---------------- kernel 2: causal flash attention (paired q-tiles) ----------------
// Swapped QK^T: S^T = mfma(K, Q) => each lane owns q-row (lane&15), kv in regs.
// Softmax register-local: 2 shfl_xor reduces, per-lane m/l scalars.
// q pre-scaled by QSCALE (log2 domain); defer-max THR=8.
__global__ __launch_bounds__(256, 4) void k_attn(
    const uint16_t* __restrict__ qws, const uint16_t* __restrict__ kws,
    const uint16_t* __restrict__ vtws, float* __restrict__ out) {
  __shared__ alignas(16) uint16_t Ksm[64 * 128];    // [kv][d]  rows 256B, swizzled
  __shared__ alignas(16) uint16_t Vsm[128 * 64];    // [d][kv]  rows 128B, swizzled
  __shared__ alignas(16) uint16_t Psm[4][16 * 64];  // per-wave [q][kv], swizzled

  int bh = blockIdx.x;                 // 0..31 : b = bh>>4, h = bh&15
  int t = threadIdx.x, w = t >> 6, l = t & 63;
  int g = l >> 4, c = l & 15;
  int bb = bh >> 4, h = bh & 15;

  const uint16_t* Qp = qws + (size_t)bh * NS * NDH;
  const uint16_t* Kp = kws + (size_t)bh * NS * NDH;
  const uint16_t* Vp = vtws + (size_t)bh * NDH * NS;

  for (int pass = 0; pass < 2; ++pass) {
    int y64 = pass ? (31 - blockIdx.y) : blockIdx.y;
    int q0 = y64 * 64;
    int r = q0 + w * 16 + c;           // this lane's q row (col of S^T)

    // hoist Q fragments (B-operand: col=lane&15=q row, k = g*8.. within kk*32)
    bf16x8 qf[4];
#pragma unroll
    for (int kk = 0; kk < 4; ++kk)
      qf[kk] = *(const bf16x8*)&Qp[(size_t)r * NDH + kk * 32 + g * 8];

    f32x4 acc_o[8];
    float mreg = -1e30f, lreg = 0.f;
#pragma unroll
    for (int n = 0; n < 8; ++n) acc_o[n] = (f32x4){0.f, 0.f, 0.f, 0.f};

    int nkt = y64 + 1;
    for (int kt = 0; kt < nkt; ++kt) {
      // stage K tile [64][128] and V^T tile [128][64]
#pragma unroll
      for (int cc = 0; cc < 4; ++cc) {
        int flat = cc * 256 + t;
        int row = flat >> 4, sub = flat & 15;
        int scol = ((sub ^ (row & 7)) << 3);
        gload_lds16(&Kp[(size_t)(kt * 64 + row) * NDH + scol], (char*)Ksm + flat * 16);
      }
#pragma unroll
      for (int cc = 0; cc < 4; ++cc) {
        int flat = cc * 256 + t;
        int row = flat >> 3, sub = flat & 7;
        int scol = ((sub ^ (row & 7)) << 3);
        gload_lds16(&Vp[(size_t)row * NS + kt * 64 + scol], (char*)Vsm + flat * 16);
      }
      __syncthreads();

      // S^T = K Q^T : sacc[nf][j] = S[q=r][kv = kt*64 + nf*16 + g*4 + j]
      f32x4 sacc[4];
#pragma unroll
      for (int nf = 0; nf < 4; ++nf) sacc[nf] = (f32x4){0.f, 0.f, 0.f, 0.f};
#pragma unroll
      for (int kk = 0; kk < 4; ++kk) {
#pragma unroll
        for (int nf = 0; nf < 4; ++nf) {
          int row = nf * 16 + c;
          int kb = ((kk * 32 + g * 8) * 2) ^ ((row & 7) << 4);
          bf16x8 kfr = *(const bf16x8*)((const char*)Ksm + row * 256 + kb);
          sacc[nf] = MFMA16(kfr, qf[kk], sacc[nf]);   // swapped operands
        }
      }

      // causal mask (diagonal tile only)
      if (kt == y64) {
#pragma unroll
        for (int nf = 0; nf < 4; ++nf)
#pragma unroll
          for (int j = 0; j < 4; ++j) {
            int kv = kt * 64 + nf * 16 + g * 4 + j;
            if (kv > r) sacc[nf][j] = -1e30f;
          }
      }

      // register-local row max (this lane's 16 kv values) + 2-shfl combine
      float mx = -1e30f;
#pragma unroll
      for (int nf = 0; nf < 4; ++nf)
        mx = fmaxf(mx, fmaxf(fmaxf(sacc[nf][0], sacc[nf][1]),
                             fmaxf(sacc[nf][2], sacc[nf][3])));
      mx = fmaxf(mx, __shfl_xor(mx, 16));
      mx = fmaxf(mx, __shfl_xor(mx, 32));

      float mnew = mreg;
      if (!__all(mx <= mreg + 8.0f)) {   // defer-max: wave-uniform rescale skip
        mnew = fmaxf(mreg, mx);
        float alpha = exp2f(mreg - mnew);
        mreg = mnew;
        lreg *= alpha;
#pragma unroll
        for (int j = 0; j < 4; ++j) {
          float aj = __shfl(alpha, (l & 48) + g * 4 + j);  // alpha of acc_o's q row
#pragma unroll
          for (int nf = 0; nf < 8; ++nf) acc_o[nf][j] *= aj;
        }
      }

      float rs = 0.f;
#pragma unroll
      for (int nf = 0; nf < 4; ++nf)
#pragma unroll
        for (int j = 0; j < 4; ++j) {
          float p = exp2f(sacc[nf][j] - mnew);
          sacc[nf][j] = p;
          rs += p;
        }
      rs += __shfl_xor(rs, 16);
      rs += __shfl_xor(rs, 32);
      lreg += rs;

      // P -> LDS (packed b32 writes): row = q = c, col = kv
#pragma unroll
      for (int nf = 0; nf < 4; ++nf) {
        uint32_t pk0 = (uint32_t)f2bf(sacc[nf][0]) | ((uint32_t)f2bf(sacc[nf][1]) << 16);
        uint32_t pk1 = (uint32_t)f2bf(sacc[nf][2]) | ((uint32_t)f2bf(sacc[nf][3]) << 16);
        int colb = (nf * 16 + g * 4) * 2;
        char* base = (char*)Psm[w] + c * 128;
        *(uint32_t*)(base + (colb ^ ((c & 7) << 4))) = pk0;
        *(uint32_t*)(base + ((colb + 4) ^ ((c & 7) << 4))) = pk1;
      }

      // O += P V   (contract over kv: 2 k-steps of 32)
#pragma unroll
      for (int kk2 = 0; kk2 < 2; ++kk2) {
        int prow = c;
        int pkb = ((kk2 * 32 + g * 8) * 2) ^ ((prow & 7) << 4);
        bf16x8 pf = *(const bf16x8*)((const char*)Psm[w] + prow * 128 + pkb);
#pragma unroll
        for (int nf = 0; nf < 8; ++nf) {
          int row = nf * 16 + c;
          int kb = ((kk2 * 32 + g * 8) * 2) ^ ((row & 7) << 4);
          bf16x8 vf = *(const bf16x8*)((const char*)Vsm + row * 128 + kb);
          acc_o[nf] = MFMA16(pf, vf, acc_o[nf]);
        }
      }
      __syncthreads();
    }

    // normalize + store fp32 out[b][s][h*128+d]
#pragma unroll
    for (int j = 0; j < 4; ++j) {
      float lj = __shfl(lreg, (l & 48) + g * 4 + j);
      float inv = 1.0f / lj;
      int s = q0 + w * 16 + g * 4 + j;
      float* op = out + ((size_t)(bb * NS + s)) * NFE + h * NDH;
#pragma unroll
      for (int nf = 0; nf < 8; ++nf) op[nf * 16 + c] = acc_o[nf][j] * inv;
    }
  }
}

extern "C" void kernel_launch(void* const* d_in, const int* in_sizes, int n_in,
                              void* d_out, int out_size, void* d_ws, size_t ws_size,
                              hipStream_t stream) {
  const float* in_q = (const float*)d_in[0];
  const float* Wq = (const float*)d_in[1];
  const float* bq = (const float*)d_in[2];
  const float* Wk = (const float*)d_in[3];
  const float* bk = (const float*)d_in[4];
  const float* Wv = (const float*)d_in[5];
  const float* bv = (const float*)d_in[6];
  // d_in[7] = mask (tril causal, hard-coded), d_in[8] = offset
  const int* offp = (const int*)d_in[8];
  float* out = (float*)d_out;

  char* ws = (char*)d_ws;
  const size_t SZ_AQ = (size_t)4096 * 2048 * 2;        // 16 MB
  const size_t SZ_WT = (size_t)3 * 2048 * 2048 * 2;    // 24 MB
  const size_t SZ_TAB = (size_t)2048 * 64 * 4;         // 512 KB
  const size_t SZ_QKV = (size_t)32 * 2048 * 128 * 2;   // 16 MB each
  uint16_t* Aq = (uint16_t*)(ws);
  uint16_t* Wt = (uint16_t*)(ws + SZ_AQ);
  float* cosT = (float*)(ws + SZ_AQ + SZ_WT);
  float* sinT = (float*)(ws + SZ_AQ + SZ_WT + SZ_TAB);
  uint16_t* qws = (uint16_t*)(ws + SZ_AQ + SZ_WT + 2 * SZ_TAB);
  uint16_t* kws = (uint16_t*)(ws + SZ_AQ + SZ_WT + 2 * SZ_TAB + SZ_QKV);
  uint16_t* vws = (uint16_t*)(ws + SZ_AQ + SZ_WT + 2 * SZ_TAB + 2 * SZ_QKV);
  uint16_t* vtws = (uint16_t*)(ws + SZ_AQ + SZ_WT + 2 * SZ_TAB + 3 * SZ_QKV);

  k_convert<<<8192, 256, 0, stream>>>(in_q, Aq);
  k_wt<<<dim3(32, 32, 3), 256, 0, stream>>>(Wq, Wk, Wv, Wt);
  k_rope_tab<<<512, 256, 0, stream>>>(cosT, sinT, offp);
  k_gemm_qkv<<<384, 512, 0, stream>>>(Aq, Wt, bq, bk, bv, cosT, sinT, qws, kws, vws);
  k_vt<<<dim3(32, 2, 32), 256, 0, stream>>>(vws, vtws);
  k_attn<<<dim3(32, 16), 256, 0, stream>>>(qws, kws, vtws, out);
}

// Round 5
// 216.587 us; speedup vs baseline: 1.0524x; 1.0524x over previous
//
#include <hip/hip_runtime.h>
#include <hip/hip_bf16.h>
#include <stdint.h>

// Problem: B=2, S=2048, F=2048, H=16, DH=128, causal, ROPE_BASE=1e4, fp32 I/O.
#define NB 2
#define NS 2048
#define NFE 2048
#define NH 16
#define NDH 128

// softmax scale folded into q (log2 domain): 1/sqrt(128) * log2(e)
#define QSCALE (0.08838834764831845f * 1.4426950408889634f)

typedef __attribute__((ext_vector_type(4))) float f32x4;
typedef __attribute__((ext_vector_type(8))) __bf16 bf16x8;

__device__ __forceinline__ uint16_t f2bf(float f) {
  uint32_t u = __builtin_bit_cast(uint32_t, f);
  return (uint16_t)((u + 0x7fffu + ((u >> 16) & 1u)) >> 16);
}

__device__ __forceinline__ void gload_lds16(const void* g, void* l) {
  __builtin_amdgcn_global_load_lds((const __attribute__((address_space(1))) void*)g,
                                   (__attribute__((address_space(3))) void*)l,
                                   16, 0, 0);
}

#define MFMA16(a, b, c) __builtin_amdgcn_mfma_f32_16x16x32_bf16(a, b, c, 0, 0, 0)

// ---------------- kernel 0a: fp32 -> bf16 convert (in_q) ----------------
__global__ void k_convert(const float* __restrict__ x, uint16_t* __restrict__ y) {
  int i = (blockIdx.x * 256 + threadIdx.x) * 4;
  float4 v = *(const float4*)(x + i);
  ushort4 o;
  o.x = f2bf(v.x); o.y = f2bf(v.y); o.z = f2bf(v.z); o.w = f2bf(v.w);
  *(ushort4*)(y + i) = o;
}

// ---------------- kernel 0b: W transpose+convert: [K][N] f32 -> [N][K] bf16 ---
__global__ void k_wt(const float* __restrict__ Wq, const float* __restrict__ Wk,
                     const float* __restrict__ Wv, uint16_t* __restrict__ Wt) {
  int which = blockIdx.z;
  const float* Wsrc = (which == 0) ? Wq : ((which == 1) ? Wk : Wv);
  int k0 = blockIdx.x * 64, n0 = blockIdx.y * 64;
  __shared__ uint16_t tile[64][65];
  int t = threadIdx.x;
#pragma unroll
  for (int it = 0; it < 4; ++it) {
    int vec = t + it * 256;        // 0..1023
    int r = vec >> 4, c4 = vec & 15;
    float4 v = *(const float4*)&Wsrc[(size_t)(k0 + r) * NFE + n0 + c4 * 4];
    tile[r][c4 * 4 + 0] = f2bf(v.x);
    tile[r][c4 * 4 + 1] = f2bf(v.y);
    tile[r][c4 * 4 + 2] = f2bf(v.z);
    tile[r][c4 * 4 + 3] = f2bf(v.w);
  }
  __syncthreads();
#pragma unroll
  for (int it = 0; it < 4; ++it) {
    int vec = t + it * 256;
    int r = vec >> 4, c4 = vec & 15;   // r = n row, c4*4 = k offset
    ushort4 o;
    o.x = tile[c4 * 4 + 0][r];
    o.y = tile[c4 * 4 + 1][r];
    o.z = tile[c4 * 4 + 2][r];
    o.w = tile[c4 * 4 + 3][r];
    *(ushort4*)&Wt[(size_t)which * NFE * NFE + (size_t)(n0 + r) * NFE + k0 + c4 * 4] = o;
  }
}

// ---------------- kernel 0c: RoPE cos/sin tables [S][64] fp32 ----------------
__global__ void k_rope_tab(float* __restrict__ cosT, float* __restrict__ sinT,
                           const int* __restrict__ offp) {
  int tid = blockIdx.x * 256 + threadIdx.x;   // 0..131071
  int s = tid >> 6, i = tid & 63;
  float off = (float)offp[0];
  float inv = expf(-((float)i / 64.0f) * logf(10000.0f));
  float ang = ((float)s + off) * inv;
  cosT[tid] = cosf(ang);
  sinT[tid] = sinf(ang);
}

// ---------------- kernel 1: QKV GEMM (128x256, 3-buffer pipelined) ----------------
// A: [4096][2048] bf16; Wt: [6144][2048] bf16 (n-major).
// Grid 768 (32 M x 24 N) = exactly 3 blocks/CU (no tail); 512 thr / 8 waves (4M x 2N):
// wave = 32 rows x 128 cols = one full head (RoPE register-local).
// BK=64; 3 LDS buffers x 48 KB = 144 KB; stage 2 K-tiles ahead; 2 phases/K-tile,
// each {10 ds_read_b128 + 3 gload_lds + 16 MFMA}; one vmcnt(6) gate per K-tile
// (always waits on loads >=2 phases old). Raw barriers only.
__global__ __launch_bounds__(512, 2) void k_gemm_qkv(
    const uint16_t* __restrict__ A, const uint16_t* __restrict__ Wt,
    const float* __restrict__ bq, const float* __restrict__ bk, const float* __restrict__ bv,
    const float* __restrict__ cosT, const float* __restrict__ sinT,
    uint16_t* __restrict__ qws, uint16_t* __restrict__ kws, uint16_t* __restrict__ vws) {
  __shared__ uint16_t SMEM[3][24576];   // buf: A [0,16KB) + B [16KB,48KB)

  int bid = blockIdx.x;
  int swzb = (bid & 7) * 96 + (bid >> 3);    // bijective: 768 % 8 == 0
  int bx = swzb & 31, by = swzb >> 5;        // bx: M-tile 0..31, by: N-tile 0..23
  int t = threadIdx.x, l = t & 63, w = t >> 6;
  int g = l >> 4, c = l & 15;
  int wr = w >> 1, wc = w & 1;

  // staging geometry: thread covers (row0 = t>>3, 16B chunk sub = t&7) per 64-row round
  int row0 = t >> 3;
  int swz = ((t & 7) ^ (row0 & 7)) << 3;     // pre-swizzled source column (elements)
  const uint16_t* aTh = A + ((size_t)bx * 128 + row0) * NFE + swz;
  const uint16_t* bTh = Wt + ((size_t)by * 256 + row0) * NFE + swz;

#define STG_A01B0(slot, u)                                   \
  do {                                                       \
    const uint16_t* _a = aTh + (size_t)(u) * 64;             \
    const uint16_t* _b = bTh + (size_t)(u) * 64;             \
    char* _d = (char*)(&SMEM[slot][0]) + t * 16;             \
    gload_lds16(_a, _d);                                     \
    gload_lds16(_a + (size_t)64 * NFE, _d + 8192);           \
    gload_lds16(_b, _d + 16384);                             \
  } while (0)
#define STG_B123(slot, u)                                    \
  do {                                                       \
    const uint16_t* _b = bTh + (size_t)(u) * 64;             \
    char* _d = (char*)(&SMEM[slot][0]) + t * 16;             \
    gload_lds16(_b + (size_t)64 * NFE, _d + 24576);          \
    gload_lds16(_b + (size_t)128 * NFE, _d + 32768);         \
    gload_lds16(_b + (size_t)192 * NFE, _d + 40960);         \
  } while (0)

#define LDA_(rb, ks)                                                              \
  _Pragma("unroll") for (int mi = 0; mi < 2; ++mi) {                              \
    int row = wr * 32 + mi * 16 + c;                                              \
    af[mi] = *(const bf16x8*)((const char*)SMEM[rb] + row * 128 +                 \
                              ((((ks) * 4 + g) ^ (row & 7)) << 4));               \
  }
#define LDB_(rb, ks)                                                              \
  _Pragma("unroll") for (int nf = 0; nf < 8; ++nf) {                              \
    int row = wc * 128 + nf * 16 + c;                                             \
    bf[nf] = *(const bf16x8*)((const char*)SMEM[rb] + 16384 + row * 128 +         \
                              ((((ks) * 4 + g) ^ (row & 7)) << 4));               \
  }
#define MM_()                                                                     \
  _Pragma("unroll") for (int mi = 0; mi < 2; ++mi)                                \
  _Pragma("unroll") for (int nf = 0; nf < 8; ++nf)                                \
    acc[mi][nf] = MFMA16(af[mi], bf[nf], acc[mi][nf]);

#define BAR_MID()                                          \
  do {                                                     \
    __builtin_amdgcn_s_barrier();                          \
    asm volatile("s_waitcnt lgkmcnt(0)" ::: "memory");     \
    __builtin_amdgcn_sched_barrier(0);                     \
    __builtin_amdgcn_s_setprio(1);                         \
  } while (0)
#define BAR_END()                                          \
  do {                                                     \
    __builtin_amdgcn_s_setprio(0);                         \
    __builtin_amdgcn_s_barrier();                          \
  } while (0)
#define VM6 asm volatile("s_waitcnt vmcnt(6)" ::: "memory")

// one K-tile: read buf rb, stage tile u into buf sb; gate G at end of phase 1
#define KTILE(rb, sb, u)                                   \
  do {                                                     \
    LDA_(rb, 0); LDB_(rb, 0);                              \
    STG_A01B0(sb, u);                                      \
    BAR_MID(); MM_(); BAR_END();                           \
    LDA_(rb, 1); LDB_(rb, 1);                              \
    STG_B123(sb, u);                                       \
    VM6;                                                   \
    BAR_MID(); MM_(); BAR_END();                           \
  } while (0)

  f32x4 acc[2][8];
#pragma unroll
  for (int m = 0; m < 2; ++m)
#pragma unroll
    for (int n = 0; n < 8; ++n) acc[m][n] = (f32x4){0.f, 0.f, 0.f, 0.f};

  bf16x8 af[2], bf[8];

  // prologue: stage T0 -> buf0, T1 -> buf1 (12 loads); T0 resident gate.
  STG_A01B0(0, 0); STG_B123(0, 0);
  STG_A01B0(1, 1); STG_B123(1, 1);
  VM6;                                       // T0's 6 retired
  __builtin_amdgcn_s_barrier();

  // main: K-tiles 0..29 (buffers t%3), staging tiles t+2 (2..31)
  for (int i = 0; i < 10; ++i) {
    int u0 = 3 * i + 2, u1 = 3 * i + 3, u2 = 3 * i + 4;
    KTILE(0, 2, u0);
    KTILE(1, 0, u1);
    KTILE(2, 1, u2);
  }

  // peeled: t=30 (buf0), t=31 (buf1); no staging
  {
    LDA_(0, 0); LDB_(0, 0);
    BAR_MID(); MM_(); BAR_END();
    LDA_(0, 1); LDB_(0, 1);
    asm volatile("s_waitcnt vmcnt(0)" ::: "memory");   // T31 resident
    BAR_MID(); MM_(); BAR_END();
    LDA_(1, 0); LDB_(1, 0);
    BAR_MID(); MM_(); BAR_END();
    LDA_(1, 1); LDB_(1, 1);
    BAR_MID(); MM_(); BAR_END();
  }

  // epilogue: wave rows [bx*128 + wr*32, +32), head ghead = by*2 + wc
  int ghead = by * 2 + wc;
  int which = ghead >> 4, h = ghead & 15;
  const float* bias = (which == 0) ? bq : ((which == 1) ? bk : bv);
  uint16_t* outp = (which == 0) ? qws : ((which == 1) ? kws : vws);
  float scl = (which == 0) ? QSCALE : 1.0f;
  int mbase = bx * 128 + wr * 32;
  if (which < 2) {
#pragma unroll
    for (int m = 0; m < 2; ++m)
#pragma unroll
      for (int nf = 0; nf < 4; ++nf) {
        int i2 = nf * 16 + c;   // rotary index 0..63
        float b1 = bias[h * NDH + i2], b2 = bias[h * NDH + 64 + i2];
#pragma unroll
        for (int j = 0; j < 4; ++j) {
          int r = mbase + m * 16 + g * 4 + j;
          int bb = r >> 11, s = r & (NS - 1);
          float cs = cosT[(s << 6) + i2], sn = sinT[(s << 6) + i2];
          float x1 = acc[m][nf][j] + b1;
          float x2 = acc[m][nf + 4][j] + b2;
          uint16_t* op = outp + ((size_t)(bb * NH + h) * NS + s) * NDH;
          op[i2] = f2bf((x1 * cs - x2 * sn) * scl);
          op[64 + i2] = f2bf((x1 * sn + x2 * cs) * scl);
        }
      }
  } else {
#pragma unroll
    for (int m = 0; m < 2; ++m)
#pragma unroll
      for (int nf = 0; nf < 8; ++nf) {
        int d = nf * 16 + c;
        float bv_ = bias[h * NDH + d];
#pragma unroll
        for (int j = 0; j < 4; ++j) {
          int r = mbase + m * 16 + g * 4 + j;
          int bb = r >> 11, s = r & (NS - 1);
          outp[((size_t)(bb * NH + h) * NS + s) * NDH + d] = f2bf(acc[m][nf][j] + bv_);
        }
      }
  }
#undef STG_A01B0
#undef STG_B123
#undef LDA_
#undef LDB_
#undef MM_
#undef BAR_MID
#undef BAR_END
#undef VM6
#undef KTILE
}

// ---------------- kernel 1.5: V transpose [bh][s][d] -> [bh][d][s] ----------------
__global__ void k_vt(const uint16_t* __restrict__ v, uint16_t* __restrict__ vt) {
  int bh = blockIdx.z;
  int s0 = blockIdx.x * 64, d0 = blockIdx.y * 64;
  __shared__ uint16_t tile[64][65];
  int t = threadIdx.x;
#pragma unroll
  for (int it = 0; it < 4; ++it) {
    int vec = t + it * 256;
    int r = vec >> 4, c4 = vec & 15;     // r = s row, c4*4 = d offset
    ushort4 x = *(const ushort4*)&v[((size_t)bh * NS + s0 + r) * NDH + d0 + c4 * 4];
    tile[r][c4 * 4 + 0] = x.x;
    tile[r][c4 * 4 + 1] = x.y;
    tile[r][c4 * 4 + 2] = x.z;
    tile[r][c4 * 4 + 3] = x.w;
  }
  __syncthreads();
#pragma unroll
  for (int it = 0; it < 4; ++it) {
    int vec = t + it * 256;
    int r = vec >> 4, c4 = vec & 15;     // r = d row, c4*4 = s offset
    ushort4 o;
    o.x = tile[c4 * 4 + 0][r];
    o.y = tile[c4 * 4 + 1][r];
    o.z = tile[c4 * 4 + 2][r];
    o.w = tile[c4 * 4 + 3][r];
    *(ushort4*)&vt[((size_t)bh * NDH + d0 + r) * NS + s0 + c4 * 4] = o;
  }
}

// ---------------- kernel 2: causal flash attention (paired q-tiles) ----------------
// Swapped QK^T: S^T = mfma(K, Q) => each lane owns q-row (lane&15), kv in regs.
// Softmax register-local: 2 shfl_xor reduces, per-lane m/l scalars.
// q pre-scaled by QSCALE (log2 domain); defer-max THR=8.
__global__ __launch_bounds__(256, 4) void k_attn(
    const uint16_t* __restrict__ qws, const uint16_t* __restrict__ kws,
    const uint16_t* __restrict__ vtws, float* __restrict__ out) {
  __shared__ alignas(16) uint16_t Ksm[64 * 128];    // [kv][d]  rows 256B, swizzled
  __shared__ alignas(16) uint16_t Vsm[128 * 64];    // [d][kv]  rows 128B, swizzled
  __shared__ alignas(16) uint16_t Psm[4][16 * 64];  // per-wave [q][kv], swizzled

  int bh = blockIdx.x;                 // 0..31 : b = bh>>4, h = bh&15
  int t = threadIdx.x, w = t >> 6, l = t & 63;
  int g = l >> 4, c = l & 15;
  int bb = bh >> 4, h = bh & 15;

  const uint16_t* Qp = qws + (size_t)bh * NS * NDH;
  const uint16_t* Kp = kws + (size_t)bh * NS * NDH;
  const uint16_t* Vp = vtws + (size_t)bh * NDH * NS;

  for (int pass = 0; pass < 2; ++pass) {
    int y64 = pass ? (31 - blockIdx.y) : blockIdx.y;
    int q0 = y64 * 64;
    int r = q0 + w * 16 + c;           // this lane's q row (col of S^T)

    // hoist Q fragments (B-operand: col=lane&15=q row, k = g*8.. within kk*32)
    bf16x8 qf[4];
#pragma unroll
    for (int kk = 0; kk < 4; ++kk)
      qf[kk] = *(const bf16x8*)&Qp[(size_t)r * NDH + kk * 32 + g * 8];

    f32x4 acc_o[8];
    float mreg = -1e30f, lreg = 0.f;
#pragma unroll
    for (int n = 0; n < 8; ++n) acc_o[n] = (f32x4){0.f, 0.f, 0.f, 0.f};

    int nkt = y64 + 1;
    for (int kt = 0; kt < nkt; ++kt) {
      // stage K tile [64][128] and V^T tile [128][64]
#pragma unroll
      for (int cc = 0; cc < 4; ++cc) {
        int flat = cc * 256 + t;
        int row = flat >> 4, sub = flat & 15;
        int scol = ((sub ^ (row & 7)) << 3);
        gload_lds16(&Kp[(size_t)(kt * 64 + row) * NDH + scol], (char*)Ksm + flat * 16);
      }
#pragma unroll
      for (int cc = 0; cc < 4; ++cc) {
        int flat = cc * 256 + t;
        int row = flat >> 3, sub = flat & 7;
        int scol = ((sub ^ (row & 7)) << 3);
        gload_lds16(&Vp[(size_t)row * NS + kt * 64 + scol], (char*)Vsm + flat * 16);
      }
      __syncthreads();

      // S^T = K Q^T : sacc[nf][j] = S[q=r][kv = kt*64 + nf*16 + g*4 + j]
      f32x4 sacc[4];
#pragma unroll
      for (int nf = 0; nf < 4; ++nf) sacc[nf] = (f32x4){0.f, 0.f, 0.f, 0.f};
#pragma unroll
      for (int kk = 0; kk < 4; ++kk) {
#pragma unroll
        for (int nf = 0; nf < 4; ++nf) {
          int row = nf * 16 + c;
          int kb = ((kk * 32 + g * 8) * 2) ^ ((row & 7) << 4);
          bf16x8 kfr = *(const bf16x8*)((const char*)Ksm + row * 256 + kb);
          sacc[nf] = MFMA16(kfr, qf[kk], sacc[nf]);   // swapped operands
        }
      }

      // causal mask (diagonal tile only)
      if (kt == y64) {
#pragma unroll
        for (int nf = 0; nf < 4; ++nf)
#pragma unroll
          for (int j = 0; j < 4; ++j) {
            int kv = kt * 64 + nf * 16 + g * 4 + j;
            if (kv > r) sacc[nf][j] = -1e30f;
          }
      }

      // register-local row max (this lane's 16 kv values) + 2-shfl combine
      float mx = -1e30f;
#pragma unroll
      for (int nf = 0; nf < 4; ++nf)
        mx = fmaxf(mx, fmaxf(fmaxf(sacc[nf][0], sacc[nf][1]),
                             fmaxf(sacc[nf][2], sacc[nf][3])));
      mx = fmaxf(mx, __shfl_xor(mx, 16));
      mx = fmaxf(mx, __shfl_xor(mx, 32));

      float mnew = mreg;
      if (!__all(mx <= mreg + 8.0f)) {   // defer-max: wave-uniform rescale skip
        mnew = fmaxf(mreg, mx);
        float alpha = exp2f(mreg - mnew);
        mreg = mnew;
        lreg *= alpha;
#pragma unroll
        for (int j = 0; j < 4; ++j) {
          float aj = __shfl(alpha, (l & 48) + g * 4 + j);  // alpha of acc_o's q row
#pragma unroll
          for (int nf = 0; nf < 8; ++nf) acc_o[nf][j] *= aj;
        }
      }

      float rs = 0.f;
#pragma unroll
      for (int nf = 0; nf < 4; ++nf)
#pragma unroll
        for (int j = 0; j < 4; ++j) {
          float p = exp2f(sacc[nf][j] - mnew);
          sacc[nf][j] = p;
          rs += p;
        }
      rs += __shfl_xor(rs, 16);
      rs += __shfl_xor(rs, 32);
      lreg += rs;

      // P -> LDS (packed b32 writes): row = q = c, col = kv
#pragma unroll
      for (int nf = 0; nf < 4; ++nf) {
        uint32_t pk0 = (uint32_t)f2bf(sacc[nf][0]) | ((uint32_t)f2bf(sacc[nf][1]) << 16);
        uint32_t pk1 = (uint32_t)f2bf(sacc[nf][2]) | ((uint32_t)f2bf(sacc[nf][3]) << 16);
        int colb = (nf * 16 + g * 4) * 2;
        char* base = (char*)Psm[w] + c * 128;
        *(uint32_t*)(base + (colb ^ ((c & 7) << 4))) = pk0;
        *(uint32_t*)(base + ((colb + 4) ^ ((c & 7) << 4))) = pk1;
      }

      // O += P V   (contract over kv: 2 k-steps of 32)
#pragma unroll
      for (int kk2 = 0; kk2 < 2; ++kk2) {
        int prow = c;
        int pkb = ((kk2 * 32 + g * 8) * 2) ^ ((prow & 7) << 4);
        bf16x8 pf = *(const bf16x8*)((const char*)Psm[w] + prow * 128 + pkb);
#pragma unroll
        for (int nf = 0; nf < 8; ++nf) {
          int row = nf * 16 + c;
          int kb = ((kk2 * 32 + g * 8) * 2) ^ ((row & 7) << 4);
          bf16x8 vf = *(const bf16x8*)((const char*)Vsm + row * 128 + kb);
          acc_o[nf] = MFMA16(pf, vf, acc_o[nf]);
        }
      }
      __syncthreads();
    }

    // normalize + store fp32 out[b][s][h*128+d]
#pragma unroll
    for (int j = 0; j < 4; ++j) {
      float lj = __shfl(lreg, (l & 48) + g * 4 + j);
      float inv = 1.0f / lj;
      int s = q0 + w * 16 + g * 4 + j;
      float* op = out + ((size_t)(bb * NS + s)) * NFE + h * NDH;
#pragma unroll
      for (int nf = 0; nf < 8; ++nf) op[nf * 16 + c] = acc_o[nf][j] * inv;
    }
  }
}

extern "C" void kernel_launch(void* const* d_in, const int* in_sizes, int n_in,
                              void* d_out, int out_size, void* d_ws, size_t ws_size,
                              hipStream_t stream) {
  const float* in_q = (const float*)d_in[0];
  const float* Wq = (const float*)d_in[1];
  const float* bq = (const float*)d_in[2];
  const float* Wk = (const float*)d_in[3];
  const float* bk = (const float*)d_in[4];
  const float* Wv = (const float*)d_in[5];
  const float* bv = (const float*)d_in[6];
  // d_in[7] = mask (tril causal, hard-coded), d_in[8] = offset
  const int* offp = (const int*)d_in[8];
  float* out = (float*)d_out;

  char* ws = (char*)d_ws;
  const size_t SZ_AQ = (size_t)4096 * 2048 * 2;        // 16 MB
  const size_t SZ_WT = (size_t)3 * 2048 * 2048 * 2;    // 24 MB
  const size_t SZ_TAB = (size_t)2048 * 64 * 4;         // 512 KB
  const size_t SZ_QKV = (size_t)32 * 2048 * 128 * 2;   // 16 MB each
  uint16_t* Aq = (uint16_t*)(ws);
  uint16_t* Wt = (uint16_t*)(ws + SZ_AQ);
  float* cosT = (float*)(ws + SZ_AQ + SZ_WT);
  float* sinT = (float*)(ws + SZ_AQ + SZ_WT + SZ_TAB);
  uint16_t* qws = (uint16_t*)(ws + SZ_AQ + SZ_WT + 2 * SZ_TAB);
  uint16_t* kws = (uint16_t*)(ws + SZ_AQ + SZ_WT + 2 * SZ_TAB + SZ_QKV);
  uint16_t* vws = (uint16_t*)(ws + SZ_AQ + SZ_WT + 2 * SZ_TAB + 2 * SZ_QKV);
  uint16_t* vtws = (uint16_t*)(ws + SZ_AQ + SZ_WT + 2 * SZ_TAB + 3 * SZ_QKV);

  k_convert<<<8192, 256, 0, stream>>>(in_q, Aq);
  k_wt<<<dim3(32, 32, 3), 256, 0, stream>>>(Wq, Wk, Wv, Wt);
  k_rope_tab<<<512, 256, 0, stream>>>(cosT, sinT, offp);
  k_gemm_qkv<<<768, 512, 0, stream>>>(Aq, Wt, bq, bk, bv, cosT, sinT, qws, kws, vws);
  k_vt<<<dim3(32, 2, 32), 256, 0, stream>>>(vws, vtws);
  k_attn<<<dim3(32, 16), 256, 0, stream>>>(qws, kws, vtws, out);
}

// Round 6
// 209.146 us; speedup vs baseline: 1.0898x; 1.0356x over previous
//
#include <hip/hip_runtime.h>
#include <hip/hip_bf16.h>
#include <stdint.h>

// Problem: B=2, S=2048, F=2048, H=16, DH=128, causal, ROPE_BASE=1e4, fp32 I/O.
#define NB 2
#define NS 2048
#define NFE 2048
#define NH 16
#define NDH 128

// softmax scale folded into q (log2 domain): 1/sqrt(128) * log2(e)
#define QSCALE (0.08838834764831845f * 1.4426950408889634f)

typedef __attribute__((ext_vector_type(4))) float f32x4;
typedef __attribute__((ext_vector_type(8))) __bf16 bf16x8;

__device__ __forceinline__ uint16_t f2bf(float f) {
  uint32_t u = __builtin_bit_cast(uint32_t, f);
  return (uint16_t)((u + 0x7fffu + ((u >> 16) & 1u)) >> 16);
}

__device__ __forceinline__ void gload_lds16(const void* g, void* l) {
  __builtin_amdgcn_global_load_lds((const __attribute__((address_space(1))) void*)g,
                                   (__attribute__((address_space(3))) void*)l,
                                   16, 0, 0);
}

#define MFMA16(a, b, c) __builtin_amdgcn_mfma_f32_16x16x32_bf16(a, b, c, 0, 0, 0)

// ---------------- kernel 0a: fp32 -> bf16 convert (in_q) + RoPE tables ----------------
__global__ void k_convert(const float* __restrict__ x, uint16_t* __restrict__ y,
                          float* __restrict__ cosT, float* __restrict__ sinT,
                          const int* __restrict__ offp) {
  int b = blockIdx.x;
  if (b < 8192) {
    int i = (b * 256 + threadIdx.x) * 4;
    float4 v = *(const float4*)(x + i);
    ushort4 o;
    o.x = f2bf(v.x); o.y = f2bf(v.y); o.z = f2bf(v.z); o.w = f2bf(v.w);
    *(ushort4*)(y + i) = o;
  } else {
    int tid = (b - 8192) * 256 + threadIdx.x;   // 0..131071
    int s = tid >> 6, i = tid & 63;
    float off = (float)offp[0];
    float inv = expf(-((float)i / 64.0f) * logf(10000.0f));
    float ang = ((float)s + off) * inv;
    cosT[tid] = cosf(ang);
    sinT[tid] = sinf(ang);
  }
}

// ---------------- kernel 0b: W transpose+convert: [K][N] f32 -> [N][K] bf16 ---
__global__ void k_wt(const float* __restrict__ Wq, const float* __restrict__ Wk,
                     const float* __restrict__ Wv, uint16_t* __restrict__ Wt) {
  int which = blockIdx.z;
  const float* Wsrc = (which == 0) ? Wq : ((which == 1) ? Wk : Wv);
  int k0 = blockIdx.x * 64, n0 = blockIdx.y * 64;
  __shared__ uint16_t tile[64][65];
  int t = threadIdx.x;
#pragma unroll
  for (int it = 0; it < 4; ++it) {
    int vec = t + it * 256;        // 0..1023
    int r = vec >> 4, c4 = vec & 15;
    float4 v = *(const float4*)&Wsrc[(size_t)(k0 + r) * NFE + n0 + c4 * 4];
    tile[r][c4 * 4 + 0] = f2bf(v.x);
    tile[r][c4 * 4 + 1] = f2bf(v.y);
    tile[r][c4 * 4 + 2] = f2bf(v.z);
    tile[r][c4 * 4 + 3] = f2bf(v.w);
  }
  __syncthreads();
#pragma unroll
  for (int it = 0; it < 4; ++it) {
    int vec = t + it * 256;
    int r = vec >> 4, c4 = vec & 15;   // r = n row, c4*4 = k offset
    ushort4 o;
    o.x = tile[c4 * 4 + 0][r];
    o.y = tile[c4 * 4 + 1][r];
    o.z = tile[c4 * 4 + 2][r];
    o.w = tile[c4 * 4 + 3][r];
    *(ushort4*)&Wt[(size_t)which * NFE * NFE + (size_t)(n0 + r) * NFE + k0 + c4 * 4] = o;
  }
}

// ---------------- kernel 1: QKV GEMM + bias + RoPE -> bf16 q/k/v ----------------
// R3-proven m97-style structure (990 TF). 128x128 tile, BK=64, 4 waves x (32x128).
// + bijective XCD swizzle (1536 % 8 == 0): each XCD chunk = 32 M x 6 N-panels.
// + launch_bounds(256,4): VGPR<=128 target (uses 64), 32KB LDS -> 4-5 blocks/CU.
__global__ __launch_bounds__(256, 4) void k_gemm_qkv(
    const uint16_t* __restrict__ A, const uint16_t* __restrict__ Wt,
    const float* __restrict__ bq, const float* __restrict__ bk, const float* __restrict__ bv,
    const float* __restrict__ cosT, const float* __restrict__ sinT,
    uint16_t* __restrict__ qws, uint16_t* __restrict__ kws, uint16_t* __restrict__ vws) {
  __shared__ alignas(16) uint16_t Asm[128 * 64];
  __shared__ alignas(16) uint16_t Bsm[128 * 64];
  int bid = blockIdx.x;                       // 0..1535
  int swzb = (bid & 7) * 192 + (bid >> 3);    // bijective XCD chunking
  int mt = swzb & 31, nt = swzb >> 5;         // mt: 0..31, nt: 0..47
  int which = nt >> 4, h = nt & 15;
  const uint16_t* Bsrc = Wt + (size_t)which * NFE * NFE + (size_t)h * NDH * NFE;
  const uint16_t* Arow = A + (size_t)mt * 128 * NFE;
  int t = threadIdx.x, w = t >> 6, l = t & 63;
  int g = l >> 4, c = l & 15;

  f32x4 acc[2][8];
#pragma unroll
  for (int m = 0; m < 2; ++m)
#pragma unroll
    for (int n = 0; n < 8; ++n) acc[m][n] = (f32x4){0.f, 0.f, 0.f, 0.f};

  for (int kt = 0; kt < NFE / 64; ++kt) {
    int k0 = kt * 64;
#pragma unroll
    for (int cc = 0; cc < 4; ++cc) {
      int flat = cc * 256 + t;         // row = flat>>3 (128B rows), sub = flat&7
      int row = flat >> 3, sub = flat & 7;
      int scol = ((sub ^ (row & 7)) << 3) + k0;
      gload_lds16(&Arow[(size_t)row * NFE + scol], (char*)Asm + flat * 16);
    }
#pragma unroll
    for (int cc = 0; cc < 4; ++cc) {
      int flat = cc * 256 + t;
      int row = flat >> 3, sub = flat & 7;
      int scol = ((sub ^ (row & 7)) << 3) + k0;
      gload_lds16(&Bsrc[(size_t)row * NFE + scol], (char*)Bsm + flat * 16);
    }
    __syncthreads();
#pragma unroll
    for (int ks = 0; ks < 2; ++ks) {
      bf16x8 af[2];
#pragma unroll
      for (int m = 0; m < 2; ++m) {
        int row = w * 32 + m * 16 + c;
        int kb = ((ks * 32 + g * 8) * 2) ^ ((row & 7) << 4);
        af[m] = *(const bf16x8*)((const char*)Asm + row * 128 + kb);
      }
#pragma unroll
      for (int nf = 0; nf < 8; ++nf) {
        int row = nf * 16 + c;
        int kb = ((ks * 32 + g * 8) * 2) ^ ((row & 7) << 4);
        bf16x8 bfr = *(const bf16x8*)((const char*)Bsm + row * 128 + kb);
        acc[0][nf] = MFMA16(af[0], bfr, acc[0][nf]);
        acc[1][nf] = MFMA16(af[1], bfr, acc[1][nf]);
      }
    }
    __syncthreads();
  }

  // epilogue: bias (+ RoPE for q,k; + QSCALE for q), write bf16 to [bh][s][d]
  const float* bias = (which == 0) ? bq : ((which == 1) ? bk : bv);
  uint16_t* outp = (which == 0) ? qws : ((which == 1) ? kws : vws);
  float scl = (which == 0) ? QSCALE : 1.0f;
  int mbase = mt * 128 + w * 32;
  if (which < 2) {
#pragma unroll
    for (int m = 0; m < 2; ++m)
#pragma unroll
      for (int nf = 0; nf < 4; ++nf) {
        int i = nf * 16 + c;   // rotary index 0..63
        float b1 = bias[h * NDH + i], b2 = bias[h * NDH + 64 + i];
#pragma unroll
        for (int j = 0; j < 4; ++j) {
          int r = mbase + m * 16 + g * 4 + j;   // global M row
          int bb = r >> 11, s = r & (NS - 1);
          float cs = cosT[(s << 6) + i], sn = sinT[(s << 6) + i];
          float x1 = acc[m][nf][j] + b1;
          float x2 = acc[m][nf + 4][j] + b2;
          uint16_t* op = outp + ((size_t)(bb * NH + h) * NS + s) * NDH;
          op[i] = f2bf((x1 * cs - x2 * sn) * scl);
          op[64 + i] = f2bf((x1 * sn + x2 * cs) * scl);
        }
      }
  } else {
#pragma unroll
    for (int m = 0; m < 2; ++m)
#pragma unroll
      for (int nf = 0; nf < 8; ++nf) {
        int d = nf * 16 + c;
        float bv_ = bias[h * NDH + d];
#pragma unroll
        for (int j = 0; j < 4; ++j) {
          int r = mbase + m * 16 + g * 4 + j;
          int bb = r >> 11, s = r & (NS - 1);
          outp[((size_t)(bb * NH + h) * NS + s) * NDH + d] = f2bf(acc[m][nf][j] + bv_);
        }
      }
  }
}

// ---------------- kernel 1.5: V transpose [bh][s][d] -> [bh][d][s] ----------------
__global__ void k_vt(const uint16_t* __restrict__ v, uint16_t* __restrict__ vt) {
  int bh = blockIdx.z;
  int s0 = blockIdx.x * 64, d0 = blockIdx.y * 64;
  __shared__ uint16_t tile[64][65];
  int t = threadIdx.x;
#pragma unroll
  for (int it = 0; it < 4; ++it) {
    int vec = t + it * 256;
    int r = vec >> 4, c4 = vec & 15;     // r = s row, c4*4 = d offset
    ushort4 x = *(const ushort4*)&v[((size_t)bh * NS + s0 + r) * NDH + d0 + c4 * 4];
    tile[r][c4 * 4 + 0] = x.x;
    tile[r][c4 * 4 + 1] = x.y;
    tile[r][c4 * 4 + 2] = x.z;
    tile[r][c4 * 4 + 3] = x.w;
  }
  __syncthreads();
#pragma unroll
  for (int it = 0; it < 4; ++it) {
    int vec = t + it * 256;
    int r = vec >> 4, c4 = vec & 15;     // r = d row, c4*4 = s offset
    ushort4 o;
    o.x = tile[c4 * 4 + 0][r];
    o.y = tile[c4 * 4 + 1][r];
    o.z = tile[c4 * 4 + 2][r];
    o.w = tile[c4 * 4 + 3][r];
    *(ushort4*)&vt[((size_t)bh * NDH + d0 + r) * NS + s0 + c4 * 4] = o;
  }
}

// ---------------- kernel 2: causal flash attention (paired q-tiles, dbuf K/V) ----------------
// Swapped QK^T: S^T = mfma(K, Q) => each lane owns q-row (lane&15), kv in regs.
// Softmax register-local; q pre-scaled by QSCALE (log2 domain); defer-max THR=8.
// K/V double-buffered: issue next tile's gload_lds BEFORE current compute (T14);
// the __syncthreads vmcnt-drain then retires loads that flew under the compute.
__global__ __launch_bounds__(256, 4) void k_attn(
    const uint16_t* __restrict__ qws, const uint16_t* __restrict__ kws,
    const uint16_t* __restrict__ vtws, float* __restrict__ out) {
  __shared__ alignas(16) uint16_t Ksm[2][64 * 128];  // [kv][d]  rows 256B, swizzled
  __shared__ alignas(16) uint16_t Vsm[2][128 * 64];  // [d][kv]  rows 128B, swizzled
  __shared__ alignas(16) uint16_t Psm[4][16 * 64];   // per-wave [q][kv], swizzled

  int bh = blockIdx.x;                 // 0..31 : b = bh>>4, h = bh&15
  int t = threadIdx.x, w = t >> 6, l = t & 63;
  int g = l >> 4, c = l & 15;
  int bb = bh >> 4, h = bh & 15;

  const uint16_t* Qp = qws + (size_t)bh * NS * NDH;
  const uint16_t* Kp = kws + (size_t)bh * NS * NDH;
  const uint16_t* Vp = vtws + (size_t)bh * NDH * NS;

#define STAGE(bb_, kt_)                                                            \
  do {                                                                             \
    _Pragma("unroll") for (int cc = 0; cc < 4; ++cc) {                             \
      int flat = cc * 256 + t;                                                     \
      int row = flat >> 4, sub = flat & 15;                                        \
      int scol = ((sub ^ (row & 7)) << 3);                                         \
      gload_lds16(&Kp[(size_t)((kt_) * 64 + row) * NDH + scol],                    \
                  (char*)Ksm[bb_] + flat * 16);                                    \
    }                                                                              \
    _Pragma("unroll") for (int cc = 0; cc < 4; ++cc) {                             \
      int flat = cc * 256 + t;                                                     \
      int row = flat >> 3, sub = flat & 7;                                         \
      int scol = ((sub ^ (row & 7)) << 3);                                         \
      gload_lds16(&Vp[(size_t)row * NS + (kt_) * 64 + scol],                       \
                  (char*)Vsm[bb_] + flat * 16);                                    \
    }                                                                              \
  } while (0)

  for (int pass = 0; pass < 2; ++pass) {
    int y64 = pass ? (31 - blockIdx.y) : blockIdx.y;
    int q0 = y64 * 64;
    int r = q0 + w * 16 + c;           // this lane's q row (col of S^T)

    // hoist Q fragments (B-operand: col=lane&15=q row, k = g*8.. within kk*32)
    bf16x8 qf[4];
#pragma unroll
    for (int kk = 0; kk < 4; ++kk)
      qf[kk] = *(const bf16x8*)&Qp[(size_t)r * NDH + kk * 32 + g * 8];

    f32x4 acc_o[8];
    float mreg = -1e30f, lreg = 0.f;
#pragma unroll
    for (int n = 0; n < 8; ++n) acc_o[n] = (f32x4){0.f, 0.f, 0.f, 0.f};

    int nkt = y64 + 1;
    STAGE(0, 0);
    __syncthreads();

    for (int kt = 0; kt < nkt; ++kt) {
      int cur = kt & 1;
      if (kt + 1 < nkt) STAGE(cur ^ 1, kt + 1);   // issue-early: hides under compute

      // S^T = K Q^T : sacc[nf][j] = S[q=r][kv = kt*64 + nf*16 + g*4 + j]
      f32x4 sacc[4];
#pragma unroll
      for (int nf = 0; nf < 4; ++nf) sacc[nf] = (f32x4){0.f, 0.f, 0.f, 0.f};
#pragma unroll
      for (int kk = 0; kk < 4; ++kk) {
#pragma unroll
        for (int nf = 0; nf < 4; ++nf) {
          int row = nf * 16 + c;
          int kb = ((kk * 32 + g * 8) * 2) ^ ((row & 7) << 4);
          bf16x8 kfr = *(const bf16x8*)((const char*)Ksm[cur] + row * 256 + kb);
          sacc[nf] = MFMA16(kfr, qf[kk], sacc[nf]);   // swapped operands
        }
      }

      // causal mask (diagonal tile only)
      if (kt == y64) {
#pragma unroll
        for (int nf = 0; nf < 4; ++nf)
#pragma unroll
          for (int j = 0; j < 4; ++j) {
            int kv = kt * 64 + nf * 16 + g * 4 + j;
            if (kv > r) sacc[nf][j] = -1e30f;
          }
      }

      // register-local row max (this lane's 16 kv values) + 2-shfl combine
      float mx = -1e30f;
#pragma unroll
      for (int nf = 0; nf < 4; ++nf)
        mx = fmaxf(mx, fmaxf(fmaxf(sacc[nf][0], sacc[nf][1]),
                             fmaxf(sacc[nf][2], sacc[nf][3])));
      mx = fmaxf(mx, __shfl_xor(mx, 16));
      mx = fmaxf(mx, __shfl_xor(mx, 32));

      float mnew = mreg;
      if (!__all(mx <= mreg + 8.0f)) {   // defer-max: wave-uniform rescale skip
        mnew = fmaxf(mreg, mx);
        float alpha = exp2f(mreg - mnew);
        mreg = mnew;
        lreg *= alpha;
#pragma unroll
        for (int j = 0; j < 4; ++j) {
          float aj = __shfl(alpha, (l & 48) + g * 4 + j);  // alpha of acc_o's q row
#pragma unroll
          for (int nf = 0; nf < 8; ++nf) acc_o[nf][j] *= aj;
        }
      }

      float rs = 0.f;
#pragma unroll
      for (int nf = 0; nf < 4; ++nf)
#pragma unroll
        for (int j = 0; j < 4; ++j) {
          float p = exp2f(sacc[nf][j] - mnew);
          sacc[nf][j] = p;
          rs += p;
        }
      rs += __shfl_xor(rs, 16);
      rs += __shfl_xor(rs, 32);
      lreg += rs;

      // P -> LDS (packed b32 writes): row = q = c, col = kv
#pragma unroll
      for (int nf = 0; nf < 4; ++nf) {
        uint32_t pk0 = (uint32_t)f2bf(sacc[nf][0]) | ((uint32_t)f2bf(sacc[nf][1]) << 16);
        uint32_t pk1 = (uint32_t)f2bf(sacc[nf][2]) | ((uint32_t)f2bf(sacc[nf][3]) << 16);
        int colb = (nf * 16 + g * 4) * 2;
        char* base = (char*)Psm[w] + c * 128;
        *(uint32_t*)(base + (colb ^ ((c & 7) << 4))) = pk0;
        *(uint32_t*)(base + ((colb + 4) ^ ((c & 7) << 4))) = pk1;
      }

      // O += P V   (contract over kv: 2 k-steps of 32)
#pragma unroll
      for (int kk2 = 0; kk2 < 2; ++kk2) {
        int prow = c;
        int pkb = ((kk2 * 32 + g * 8) * 2) ^ ((prow & 7) << 4);
        bf16x8 pf = *(const bf16x8*)((const char*)Psm[w] + prow * 128 + pkb);
#pragma unroll
        for (int nf = 0; nf < 8; ++nf) {
          int row = nf * 16 + c;
          int kb = ((kk2 * 32 + g * 8) * 2) ^ ((row & 7) << 4);
          bf16x8 vf = *(const bf16x8*)((const char*)Vsm[cur] + row * 128 + kb);
          acc_o[nf] = MFMA16(pf, vf, acc_o[nf]);
        }
      }
      __syncthreads();   // drains vmcnt (staged loads) + gates buffer reuse
    }

    // normalize + store fp32 out[b][s][h*128+d]
#pragma unroll
    for (int j = 0; j < 4; ++j) {
      float lj = __shfl(lreg, (l & 48) + g * 4 + j);
      float inv = 1.0f / lj;
      int s = q0 + w * 16 + g * 4 + j;
      float* op = out + ((size_t)(bb * NS + s)) * NFE + h * NDH;
#pragma unroll
      for (int nf = 0; nf < 8; ++nf) op[nf * 16 + c] = acc_o[nf][j] * inv;
    }
  }
#undef STAGE
}

extern "C" void kernel_launch(void* const* d_in, const int* in_sizes, int n_in,
                              void* d_out, int out_size, void* d_ws, size_t ws_size,
                              hipStream_t stream) {
  const float* in_q = (const float*)d_in[0];
  const float* Wq = (const float*)d_in[1];
  const float* bq = (const float*)d_in[2];
  const float* Wk = (const float*)d_in[3];
  const float* bk = (const float*)d_in[4];
  const float* Wv = (const float*)d_in[5];
  const float* bv = (const float*)d_in[6];
  // d_in[7] = mask (tril causal, hard-coded), d_in[8] = offset
  const int* offp = (const int*)d_in[8];
  float* out = (float*)d_out;

  char* ws = (char*)d_ws;
  const size_t SZ_AQ = (size_t)4096 * 2048 * 2;        // 16 MB
  const size_t SZ_WT = (size_t)3 * 2048 * 2048 * 2;    // 24 MB
  const size_t SZ_TAB = (size_t)2048 * 64 * 4;         // 512 KB
  const size_t SZ_QKV = (size_t)32 * 2048 * 128 * 2;   // 16 MB each
  uint16_t* Aq = (uint16_t*)(ws);
  uint16_t* Wt = (uint16_t*)(ws + SZ_AQ);
  float* cosT = (float*)(ws + SZ_AQ + SZ_WT);
  float* sinT = (float*)(ws + SZ_AQ + SZ_WT + SZ_TAB);
  uint16_t* qws = (uint16_t*)(ws + SZ_AQ + SZ_WT + 2 * SZ_TAB);
  uint16_t* kws = (uint16_t*)(ws + SZ_AQ + SZ_WT + 2 * SZ_TAB + SZ_QKV);
  uint16_t* vws = (uint16_t*)(ws + SZ_AQ + SZ_WT + 2 * SZ_TAB + 2 * SZ_QKV);
  uint16_t* vtws = (uint16_t*)(ws + SZ_AQ + SZ_WT + 2 * SZ_TAB + 3 * SZ_QKV);

  k_convert<<<8704, 256, 0, stream>>>(in_q, Aq, cosT, sinT, offp);
  k_wt<<<dim3(32, 32, 3), 256, 0, stream>>>(Wq, Wk, Wv, Wt);
  k_gemm_qkv<<<1536, 256, 0, stream>>>(Aq, Wt, bq, bk, bv, cosT, sinT, qws, kws, vws);
  k_vt<<<dim3(32, 2, 32), 256, 0, stream>>>(vws, vtws);
  k_attn<<<dim3(32, 16), 256, 0, stream>>>(qws, kws, vtws, out);
}

// Round 7
// 200.826 us; speedup vs baseline: 1.1350x; 1.0414x over previous
//
#include <hip/hip_runtime.h>
#include <hip/hip_bf16.h>
#include <stdint.h>

// Problem: B=2, S=2048, F=2048, H=16, DH=128, causal, ROPE_BASE=1e4, fp32 I/O.
#define NB 2
#define NS 2048
#define NFE 2048
#define NH 16
#define NDH 128

// softmax scale folded into q (log2 domain): 1/sqrt(128) * log2(e)
#define QSCALE (0.08838834764831845f * 1.4426950408889634f)

typedef __attribute__((ext_vector_type(4))) float f32x4;
typedef __attribute__((ext_vector_type(8))) __bf16 bf16x8;

__device__ __forceinline__ uint16_t f2bf(float f) {
  uint32_t u = __builtin_bit_cast(uint32_t, f);
  return (uint16_t)((u + 0x7fffu + ((u >> 16) & 1u)) >> 16);
}

__device__ __forceinline__ void gload_lds16(const void* g, void* l) {
  __builtin_amdgcn_global_load_lds((const __attribute__((address_space(1))) void*)g,
                                   (__attribute__((address_space(3))) void*)l,
                                   16, 0, 0);
}

#define MFMA16(a, b, c) __builtin_amdgcn_mfma_f32_16x16x32_bf16(a, b, c, 0, 0, 0)

// ---------------- kernel 0a: fp32 -> bf16 convert (in_q) + RoPE tables ----------------
__global__ void k_convert(const float* __restrict__ x, uint16_t* __restrict__ y,
                          float* __restrict__ cosT, float* __restrict__ sinT,
                          const int* __restrict__ offp) {
  int b = blockIdx.x;
  if (b < 8192) {
    int i = (b * 256 + threadIdx.x) * 4;
    float4 v = *(const float4*)(x + i);
    ushort4 o;
    o.x = f2bf(v.x); o.y = f2bf(v.y); o.z = f2bf(v.z); o.w = f2bf(v.w);
    *(ushort4*)(y + i) = o;
  } else {
    int tid = (b - 8192) * 256 + threadIdx.x;   // 0..131071
    int s = tid >> 6, i = tid & 63;
    float off = (float)offp[0];
    float inv = expf(-((float)i / 64.0f) * logf(10000.0f));
    float ang = ((float)s + off) * inv;
    cosT[tid] = cosf(ang);
    sinT[tid] = sinf(ang);
  }
}

// ---------------- kernel 0b: W transpose+convert: [K][N] f32 -> [N][K] bf16 ---
__global__ void k_wt(const float* __restrict__ Wq, const float* __restrict__ Wk,
                     const float* __restrict__ Wv, uint16_t* __restrict__ Wt) {
  int which = blockIdx.z;
  const float* Wsrc = (which == 0) ? Wq : ((which == 1) ? Wk : Wv);
  int k0 = blockIdx.x * 64, n0 = blockIdx.y * 64;
  __shared__ uint16_t tile[64][65];
  int t = threadIdx.x;
#pragma unroll
  for (int it = 0; it < 4; ++it) {
    int vec = t + it * 256;        // 0..1023
    int r = vec >> 4, c4 = vec & 15;
    float4 v = *(const float4*)&Wsrc[(size_t)(k0 + r) * NFE + n0 + c4 * 4];
    tile[r][c4 * 4 + 0] = f2bf(v.x);
    tile[r][c4 * 4 + 1] = f2bf(v.y);
    tile[r][c4 * 4 + 2] = f2bf(v.z);
    tile[r][c4 * 4 + 3] = f2bf(v.w);
  }
  __syncthreads();
#pragma unroll
  for (int it = 0; it < 4; ++it) {
    int vec = t + it * 256;
    int r = vec >> 4, c4 = vec & 15;   // r = n row, c4*4 = k offset
    ushort4 o;
    o.x = tile[c4 * 4 + 0][r];
    o.y = tile[c4 * 4 + 1][r];
    o.z = tile[c4 * 4 + 2][r];
    o.w = tile[c4 * 4 + 3][r];
    *(ushort4*)&Wt[(size_t)which * NFE * NFE + (size_t)(n0 + r) * NFE + k0 + c4 * 4] = o;
  }
}

// ---------------- kernel 1: QKV GEMM + bias + RoPE -> bf16 q/k/v ----------------
// R3-proven m97-style structure (measured 104-110us / ~990 TF). 128x128 tile, BK=64,
// 4 waves x (32x128); grid (32,48) mt-fastest (measured best L2 behavior, FETCH~117MB).
// NOTE (R6 lesson): XCD nt-chunking thrashes L2 (FETCH 214MB, +20us) — K=2048 panels
// are 512KB; no 2D chunk fits the 4MB XCD L2. Default order + L3 wins.
__global__ __launch_bounds__(256, 2) void k_gemm_qkv(
    const uint16_t* __restrict__ A, const uint16_t* __restrict__ Wt,
    const float* __restrict__ bq, const float* __restrict__ bk, const float* __restrict__ bv,
    const float* __restrict__ cosT, const float* __restrict__ sinT,
    uint16_t* __restrict__ qws, uint16_t* __restrict__ kws, uint16_t* __restrict__ vws) {
  __shared__ alignas(16) uint16_t Asm[128 * 64];
  __shared__ alignas(16) uint16_t Bsm[128 * 64];
  int mt = blockIdx.x;                 // 0..31
  int nt = blockIdx.y;                 // 0..47
  int which = nt >> 4, h = nt & 15;
  const uint16_t* Bsrc = Wt + (size_t)which * NFE * NFE + (size_t)h * NDH * NFE;
  const uint16_t* Arow = A + (size_t)mt * 128 * NFE;
  int t = threadIdx.x, w = t >> 6, l = t & 63;
  int g = l >> 4, c = l & 15;

  f32x4 acc[2][8];
#pragma unroll
  for (int m = 0; m < 2; ++m)
#pragma unroll
    for (int n = 0; n < 8; ++n) acc[m][n] = (f32x4){0.f, 0.f, 0.f, 0.f};

  for (int kt = 0; kt < NFE / 64; ++kt) {
    int k0 = kt * 64;
#pragma unroll
    for (int cc = 0; cc < 4; ++cc) {
      int flat = cc * 256 + t;         // row = flat>>3 (128B rows), sub = flat&7
      int row = flat >> 3, sub = flat & 7;
      int scol = ((sub ^ (row & 7)) << 3) + k0;
      gload_lds16(&Arow[(size_t)row * NFE + scol], (char*)Asm + flat * 16);
    }
#pragma unroll
    for (int cc = 0; cc < 4; ++cc) {
      int flat = cc * 256 + t;
      int row = flat >> 3, sub = flat & 7;
      int scol = ((sub ^ (row & 7)) << 3) + k0;
      gload_lds16(&Bsrc[(size_t)row * NFE + scol], (char*)Bsm + flat * 16);
    }
    __syncthreads();
#pragma unroll
    for (int ks = 0; ks < 2; ++ks) {
      bf16x8 af[2];
#pragma unroll
      for (int m = 0; m < 2; ++m) {
        int row = w * 32 + m * 16 + c;
        int kb = ((ks * 32 + g * 8) * 2) ^ ((row & 7) << 4);
        af[m] = *(const bf16x8*)((const char*)Asm + row * 128 + kb);
      }
#pragma unroll
      for (int nf = 0; nf < 8; ++nf) {
        int row = nf * 16 + c;
        int kb = ((ks * 32 + g * 8) * 2) ^ ((row & 7) << 4);
        bf16x8 bfr = *(const bf16x8*)((const char*)Bsm + row * 128 + kb);
        acc[0][nf] = MFMA16(af[0], bfr, acc[0][nf]);
        acc[1][nf] = MFMA16(af[1], bfr, acc[1][nf]);
      }
    }
    __syncthreads();
  }

  // epilogue: bias (+ RoPE for q,k; + QSCALE for q), write bf16 to [bh][s][d]
  const float* bias = (which == 0) ? bq : ((which == 1) ? bk : bv);
  uint16_t* outp = (which == 0) ? qws : ((which == 1) ? kws : vws);
  float scl = (which == 0) ? QSCALE : 1.0f;
  int mbase = mt * 128 + w * 32;
  if (which < 2) {
#pragma unroll
    for (int m = 0; m < 2; ++m)
#pragma unroll
      for (int nf = 0; nf < 4; ++nf) {
        int i = nf * 16 + c;   // rotary index 0..63
        float b1 = bias[h * NDH + i], b2 = bias[h * NDH + 64 + i];
#pragma unroll
        for (int j = 0; j < 4; ++j) {
          int r = mbase + m * 16 + g * 4 + j;   // global M row
          int bb = r >> 11, s = r & (NS - 1);
          float cs = cosT[(s << 6) + i], sn = sinT[(s << 6) + i];
          float x1 = acc[m][nf][j] + b1;
          float x2 = acc[m][nf + 4][j] + b2;
          uint16_t* op = outp + ((size_t)(bb * NH + h) * NS + s) * NDH;
          op[i] = f2bf((x1 * cs - x2 * sn) * scl);
          op[64 + i] = f2bf((x1 * sn + x2 * cs) * scl);
        }
      }
  } else {
#pragma unroll
    for (int m = 0; m < 2; ++m)
#pragma unroll
      for (int nf = 0; nf < 8; ++nf) {
        int d = nf * 16 + c;
        float bv_ = bias[h * NDH + d];
#pragma unroll
        for (int j = 0; j < 4; ++j) {
          int r = mbase + m * 16 + g * 4 + j;
          int bb = r >> 11, s = r & (NS - 1);
          outp[((size_t)(bb * NH + h) * NS + s) * NDH + d] = f2bf(acc[m][nf][j] + bv_);
        }
      }
  }
}

// ---------------- kernel 1.5: V transpose [bh][s][d] -> [bh][d][s] ----------------
__global__ void k_vt(const uint16_t* __restrict__ v, uint16_t* __restrict__ vt) {
  int bh = blockIdx.z;
  int s0 = blockIdx.x * 64, d0 = blockIdx.y * 64;
  __shared__ uint16_t tile[64][65];
  int t = threadIdx.x;
#pragma unroll
  for (int it = 0; it < 4; ++it) {
    int vec = t + it * 256;
    int r = vec >> 4, c4 = vec & 15;     // r = s row, c4*4 = d offset
    ushort4 x = *(const ushort4*)&v[((size_t)bh * NS + s0 + r) * NDH + d0 + c4 * 4];
    tile[r][c4 * 4 + 0] = x.x;
    tile[r][c4 * 4 + 1] = x.y;
    tile[r][c4 * 4 + 2] = x.z;
    tile[r][c4 * 4 + 3] = x.w;
  }
  __syncthreads();
#pragma unroll
  for (int it = 0; it < 4; ++it) {
    int vec = t + it * 256;
    int r = vec >> 4, c4 = vec & 15;     // r = d row, c4*4 = s offset
    ushort4 o;
    o.x = tile[c4 * 4 + 0][r];
    o.y = tile[c4 * 4 + 1][r];
    o.z = tile[c4 * 4 + 2][r];
    o.w = tile[c4 * 4 + 3][r];
    *(ushort4*)&vt[((size_t)bh * NDH + d0 + r) * NS + s0 + c4 * 4] = o;
  }
}

// ---------------- kernel 2: causal flash attention (paired q-tiles, dbuf K/V) ----------------
// Swapped QK^T: S^T = mfma(K, Q) => each lane owns q-row (lane&15), kv in regs.
// Softmax register-local; q pre-scaled by QSCALE (log2 domain); defer-max THR=8.
// K/V double-buffered: issue next tile's gload_lds BEFORE current compute (T14);
// the __syncthreads vmcnt-drain then retires loads that flew under the compute.
__global__ __launch_bounds__(256, 4) void k_attn(
    const uint16_t* __restrict__ qws, const uint16_t* __restrict__ kws,
    const uint16_t* __restrict__ vtws, float* __restrict__ out) {
  __shared__ alignas(16) uint16_t Ksm[2][64 * 128];  // [kv][d]  rows 256B, swizzled
  __shared__ alignas(16) uint16_t Vsm[2][128 * 64];  // [d][kv]  rows 128B, swizzled
  __shared__ alignas(16) uint16_t Psm[4][16 * 64];   // per-wave [q][kv], swizzled

  int bh = blockIdx.x;                 // 0..31 : b = bh>>4, h = bh&15
  int t = threadIdx.x, w = t >> 6, l = t & 63;
  int g = l >> 4, c = l & 15;
  int bb = bh >> 4, h = bh & 15;

  const uint16_t* Qp = qws + (size_t)bh * NS * NDH;
  const uint16_t* Kp = kws + (size_t)bh * NS * NDH;
  const uint16_t* Vp = vtws + (size_t)bh * NDH * NS;

#define STAGE(bb_, kt_)                                                            \
  do {                                                                             \
    _Pragma("unroll") for (int cc = 0; cc < 4; ++cc) {                             \
      int flat = cc * 256 + t;                                                     \
      int row = flat >> 4, sub = flat & 15;                                        \
      int scol = ((sub ^ (row & 7)) << 3);                                         \
      gload_lds16(&Kp[(size_t)((kt_) * 64 + row) * NDH + scol],                    \
                  (char*)Ksm[bb_] + flat * 16);                                    \
    }                                                                              \
    _Pragma("unroll") for (int cc = 0; cc < 4; ++cc) {                             \
      int flat = cc * 256 + t;                                                     \
      int row = flat >> 3, sub = flat & 7;                                         \
      int scol = ((sub ^ (row & 7)) << 3);                                         \
      gload_lds16(&Vp[(size_t)row * NS + (kt_) * 64 + scol],                       \
                  (char*)Vsm[bb_] + flat * 16);                                    \
    }                                                                              \
  } while (0)

  for (int pass = 0; pass < 2; ++pass) {
    int y64 = pass ? (31 - blockIdx.y) : blockIdx.y;
    int q0 = y64 * 64;
    int r = q0 + w * 16 + c;           // this lane's q row (col of S^T)

    // hoist Q fragments (B-operand: col=lane&15=q row, k = g*8.. within kk*32)
    bf16x8 qf[4];
#pragma unroll
    for (int kk = 0; kk < 4; ++kk)
      qf[kk] = *(const bf16x8*)&Qp[(size_t)r * NDH + kk * 32 + g * 8];

    f32x4 acc_o[8];
    float mreg = -1e30f, lreg = 0.f;
#pragma unroll
    for (int n = 0; n < 8; ++n) acc_o[n] = (f32x4){0.f, 0.f, 0.f, 0.f};

    int nkt = y64 + 1;
    STAGE(0, 0);
    __syncthreads();

    for (int kt = 0; kt < nkt; ++kt) {
      int cur = kt & 1;
      if (kt + 1 < nkt) STAGE(cur ^ 1, kt + 1);   // issue-early: hides under compute

      // S^T = K Q^T : sacc[nf][j] = S[q=r][kv = kt*64 + nf*16 + g*4 + j]
      f32x4 sacc[4];
#pragma unroll
      for (int nf = 0; nf < 4; ++nf) sacc[nf] = (f32x4){0.f, 0.f, 0.f, 0.f};
#pragma unroll
      for (int kk = 0; kk < 4; ++kk) {
#pragma unroll
        for (int nf = 0; nf < 4; ++nf) {
          int row = nf * 16 + c;
          int kb = ((kk * 32 + g * 8) * 2) ^ ((row & 7) << 4);
          bf16x8 kfr = *(const bf16x8*)((const char*)Ksm[cur] + row * 256 + kb);
          sacc[nf] = MFMA16(kfr, qf[kk], sacc[nf]);   // swapped operands
        }
      }

      // causal mask (diagonal tile only)
      if (kt == y64) {
#pragma unroll
        for (int nf = 0; nf < 4; ++nf)
#pragma unroll
          for (int j = 0; j < 4; ++j) {
            int kv = kt * 64 + nf * 16 + g * 4 + j;
            if (kv > r) sacc[nf][j] = -1e30f;
          }
      }

      // register-local row max (this lane's 16 kv values) + 2-shfl combine
      float mx = -1e30f;
#pragma unroll
      for (int nf = 0; nf < 4; ++nf)
        mx = fmaxf(mx, fmaxf(fmaxf(sacc[nf][0], sacc[nf][1]),
                             fmaxf(sacc[nf][2], sacc[nf][3])));
      mx = fmaxf(mx, __shfl_xor(mx, 16));
      mx = fmaxf(mx, __shfl_xor(mx, 32));

      float mnew = mreg;
      if (!__all(mx <= mreg + 8.0f)) {   // defer-max: wave-uniform rescale skip
        mnew = fmaxf(mreg, mx);
        float alpha = exp2f(mreg - mnew);
        mreg = mnew;
        lreg *= alpha;
#pragma unroll
        for (int j = 0; j < 4; ++j) {
          float aj = __shfl(alpha, (l & 48) + g * 4 + j);  // alpha of acc_o's q row
#pragma unroll
          for (int nf = 0; nf < 8; ++nf) acc_o[nf][j] *= aj;
        }
      }

      float rs = 0.f;
#pragma unroll
      for (int nf = 0; nf < 4; ++nf)
#pragma unroll
        for (int j = 0; j < 4; ++j) {
          float p = exp2f(sacc[nf][j] - mnew);
          sacc[nf][j] = p;
          rs += p;
        }
      rs += __shfl_xor(rs, 16);
      rs += __shfl_xor(rs, 32);
      lreg += rs;

      // P -> LDS (packed b32 writes): row = q = c, col = kv
#pragma unroll
      for (int nf = 0; nf < 4; ++nf) {
        uint32_t pk0 = (uint32_t)f2bf(sacc[nf][0]) | ((uint32_t)f2bf(sacc[nf][1]) << 16);
        uint32_t pk1 = (uint32_t)f2bf(sacc[nf][2]) | ((uint32_t)f2bf(sacc[nf][3]) << 16);
        int colb = (nf * 16 + g * 4) * 2;
        char* base = (char*)Psm[w] + c * 128;
        *(uint32_t*)(base + (colb ^ ((c & 7) << 4))) = pk0;
        *(uint32_t*)(base + ((colb + 4) ^ ((c & 7) << 4))) = pk1;
      }

      // O += P V   (contract over kv: 2 k-steps of 32)
#pragma unroll
      for (int kk2 = 0; kk2 < 2; ++kk2) {
        int prow = c;
        int pkb = ((kk2 * 32 + g * 8) * 2) ^ ((prow & 7) << 4);
        bf16x8 pf = *(const bf16x8*)((const char*)Psm[w] + prow * 128 + pkb);
#pragma unroll
        for (int nf = 0; nf < 8; ++nf) {
          int row = nf * 16 + c;
          int kb = ((kk2 * 32 + g * 8) * 2) ^ ((row & 7) << 4);
          bf16x8 vf = *(const bf16x8*)((const char*)Vsm[cur] + row * 128 + kb);
          acc_o[nf] = MFMA16(pf, vf, acc_o[nf]);
        }
      }
      __syncthreads();   // drains vmcnt (staged loads) + gates buffer reuse
    }

    // normalize + store fp32 out[b][s][h*128+d]
#pragma unroll
    for (int j = 0; j < 4; ++j) {
      float lj = __shfl(lreg, (l & 48) + g * 4 + j);
      float inv = 1.0f / lj;
      int s = q0 + w * 16 + g * 4 + j;
      float* op = out + ((size_t)(bb * NS + s)) * NFE + h * NDH;
#pragma unroll
      for (int nf = 0; nf < 8; ++nf) op[nf * 16 + c] = acc_o[nf][j] * inv;
    }
  }
#undef STAGE
}

extern "C" void kernel_launch(void* const* d_in, const int* in_sizes, int n_in,
                              void* d_out, int out_size, void* d_ws, size_t ws_size,
                              hipStream_t stream) {
  const float* in_q = (const float*)d_in[0];
  const float* Wq = (const float*)d_in[1];
  const float* bq = (const float*)d_in[2];
  const float* Wk = (const float*)d_in[3];
  const float* bk = (const float*)d_in[4];
  const float* Wv = (const float*)d_in[5];
  const float* bv = (const float*)d_in[6];
  // d_in[7] = mask (tril causal, hard-coded), d_in[8] = offset
  const int* offp = (const int*)d_in[8];
  float* out = (float*)d_out;

  char* ws = (char*)d_ws;
  const size_t SZ_AQ = (size_t)4096 * 2048 * 2;        // 16 MB
  const size_t SZ_WT = (size_t)3 * 2048 * 2048 * 2;    // 24 MB
  const size_t SZ_TAB = (size_t)2048 * 64 * 4;         // 512 KB
  const size_t SZ_QKV = (size_t)32 * 2048 * 128 * 2;   // 16 MB each
  uint16_t* Aq = (uint16_t*)(ws);
  uint16_t* Wt = (uint16_t*)(ws + SZ_AQ);
  float* cosT = (float*)(ws + SZ_AQ + SZ_WT);
  float* sinT = (float*)(ws + SZ_AQ + SZ_WT + SZ_TAB);
  uint16_t* qws = (uint16_t*)(ws + SZ_AQ + SZ_WT + 2 * SZ_TAB);
  uint16_t* kws = (uint16_t*)(ws + SZ_AQ + SZ_WT + 2 * SZ_TAB + SZ_QKV);
  uint16_t* vws = (uint16_t*)(ws + SZ_AQ + SZ_WT + 2 * SZ_TAB + 2 * SZ_QKV);
  uint16_t* vtws = (uint16_t*)(ws + SZ_AQ + SZ_WT + 2 * SZ_TAB + 3 * SZ_QKV);

  k_convert<<<8704, 256, 0, stream>>>(in_q, Aq, cosT, sinT, offp);
  k_wt<<<dim3(32, 32, 3), 256, 0, stream>>>(Wq, Wk, Wv, Wt);
  k_gemm_qkv<<<dim3(32, 48), 256, 0, stream>>>(Aq, Wt, bq, bk, bv, cosT, sinT, qws, kws, vws);
  k_vt<<<dim3(32, 2, 32), 256, 0, stream>>>(vws, vtws);
  k_attn<<<dim3(32, 16), 256, 0, stream>>>(qws, kws, vtws, out);
}

// Round 8
// 190.665 us; speedup vs baseline: 1.1955x; 1.0533x over previous
//
#include <hip/hip_runtime.h>
#include <hip/hip_bf16.h>
#include <stdint.h>

// Problem: B=2, S=2048, F=2048, H=16, DH=128, causal, ROPE_BASE=1e4, fp32 I/O.
#define NB 2
#define NS 2048
#define NFE 2048
#define NH 16
#define NDH 128

// softmax scale folded into q (log2 domain): 1/sqrt(128) * log2(e)
#define QSCALE (0.08838834764831845f * 1.4426950408889634f)

typedef __attribute__((ext_vector_type(4))) float f32x4;
typedef __attribute__((ext_vector_type(8))) __bf16 bf16x8;

__device__ __forceinline__ uint16_t f2bf(float f) {
  uint32_t u = __builtin_bit_cast(uint32_t, f);
  return (uint16_t)((u + 0x7fffu + ((u >> 16) & 1u)) >> 16);
}

__device__ __forceinline__ void gload_lds16(const void* g, void* l) {
  __builtin_amdgcn_global_load_lds((const __attribute__((address_space(1))) void*)g,
                                   (__attribute__((address_space(3))) void*)l,
                                   16, 0, 0);
}

#define MFMA16(a, b, c) __builtin_amdgcn_mfma_f32_16x16x32_bf16(a, b, c, 0, 0, 0)

// ---------------- kernel 0: fused prep ----------------
// blocks [0,8192): fp32->bf16 convert of in_q
// blocks [8192,8704): RoPE cos/sin tables [S][64]
// blocks [8704,11776): W transpose+convert [K][N] f32 -> [N][K] bf16 (3 x 1024 tiles)
__global__ void k_prep(const float* __restrict__ x, uint16_t* __restrict__ y,
                       float* __restrict__ cosT, float* __restrict__ sinT,
                       const int* __restrict__ offp,
                       const float* __restrict__ Wq, const float* __restrict__ Wk,
                       const float* __restrict__ Wv, uint16_t* __restrict__ Wt) {
  __shared__ uint16_t tile[64][65];
  int b = blockIdx.x;
  int t = threadIdx.x;
  if (b < 8192) {
    int i = (b * 256 + t) * 4;
    float4 v = *(const float4*)(x + i);
    ushort4 o;
    o.x = f2bf(v.x); o.y = f2bf(v.y); o.z = f2bf(v.z); o.w = f2bf(v.w);
    *(ushort4*)(y + i) = o;
  } else if (b < 8704) {
    int tid = (b - 8192) * 256 + t;   // 0..131071
    int s = tid >> 6, i = tid & 63;
    float off = (float)offp[0];
    float inv = expf(-((float)i / 64.0f) * logf(10000.0f));
    float ang = ((float)s + off) * inv;
    cosT[tid] = cosf(ang);
    sinT[tid] = sinf(ang);
  } else {
    int idx = b - 8704;               // 0..3071
    int which = idx >> 10, rem = idx & 1023;
    int k0 = (rem & 31) * 64, n0 = (rem >> 5) * 64;
    const float* Wsrc = (which == 0) ? Wq : ((which == 1) ? Wk : Wv);
#pragma unroll
    for (int it = 0; it < 4; ++it) {
      int vec = t + it * 256;        // 0..1023
      int r = vec >> 4, c4 = vec & 15;
      float4 v = *(const float4*)&Wsrc[(size_t)(k0 + r) * NFE + n0 + c4 * 4];
      tile[r][c4 * 4 + 0] = f2bf(v.x);
      tile[r][c4 * 4 + 1] = f2bf(v.y);
      tile[r][c4 * 4 + 2] = f2bf(v.z);
      tile[r][c4 * 4 + 3] = f2bf(v.w);
    }
    __syncthreads();
#pragma unroll
    for (int it = 0; it < 4; ++it) {
      int vec = t + it * 256;
      int r = vec >> 4, c4 = vec & 15;   // r = n row, c4*4 = k offset
      ushort4 o;
      o.x = tile[c4 * 4 + 0][r];
      o.y = tile[c4 * 4 + 1][r];
      o.z = tile[c4 * 4 + 2][r];
      o.w = tile[c4 * 4 + 3][r];
      *(ushort4*)&Wt[(size_t)which * NFE * NFE + (size_t)(n0 + r) * NFE + k0 + c4 * 4] = o;
    }
  }
}

// ---------------- kernel 1: QKV GEMM + bias + RoPE (+ fused V-transpose) ----------------
// R3-proven m97-style structure (measured 104-110us / ~990 TF). 128x128 tile, BK=64,
// 4 waves x (32x128); grid (32,48) mt-fastest (measured best L2, FETCH~117MB).
// which==2 (v) blocks transpose in the dead staging LDS and write vt[bh][d][s] directly.
__global__ __launch_bounds__(256, 2) void k_gemm_qkv(
    const uint16_t* __restrict__ A, const uint16_t* __restrict__ Wt,
    const float* __restrict__ bq, const float* __restrict__ bk, const float* __restrict__ bv,
    const float* __restrict__ cosT, const float* __restrict__ sinT,
    uint16_t* __restrict__ qws, uint16_t* __restrict__ kws, uint16_t* __restrict__ vtws) {
  __shared__ alignas(16) uint16_t SM[2 * 128 * 64];   // Asm = SM, Bsm = SM+8192
  uint16_t* Asm = SM;
  uint16_t* Bsm = SM + 8192;
  int mt = blockIdx.x;                 // 0..31
  int nt = blockIdx.y;                 // 0..47
  int which = nt >> 4, h = nt & 15;
  const uint16_t* Bsrc = Wt + (size_t)which * NFE * NFE + (size_t)h * NDH * NFE;
  const uint16_t* Arow = A + (size_t)mt * 128 * NFE;
  int t = threadIdx.x, w = t >> 6, l = t & 63;
  int g = l >> 4, c = l & 15;

  f32x4 acc[2][8];
#pragma unroll
  for (int m = 0; m < 2; ++m)
#pragma unroll
    for (int n = 0; n < 8; ++n) acc[m][n] = (f32x4){0.f, 0.f, 0.f, 0.f};

  for (int kt = 0; kt < NFE / 64; ++kt) {
    int k0 = kt * 64;
#pragma unroll
    for (int cc = 0; cc < 4; ++cc) {
      int flat = cc * 256 + t;         // row = flat>>3 (128B rows), sub = flat&7
      int row = flat >> 3, sub = flat & 7;
      int scol = ((sub ^ (row & 7)) << 3) + k0;
      gload_lds16(&Arow[(size_t)row * NFE + scol], (char*)Asm + flat * 16);
    }
#pragma unroll
    for (int cc = 0; cc < 4; ++cc) {
      int flat = cc * 256 + t;
      int row = flat >> 3, sub = flat & 7;
      int scol = ((sub ^ (row & 7)) << 3) + k0;
      gload_lds16(&Bsrc[(size_t)row * NFE + scol], (char*)Bsm + flat * 16);
    }
    __syncthreads();
#pragma unroll
    for (int ks = 0; ks < 2; ++ks) {
      bf16x8 af[2];
#pragma unroll
      for (int m = 0; m < 2; ++m) {
        int row = w * 32 + m * 16 + c;
        int kb = ((ks * 32 + g * 8) * 2) ^ ((row & 7) << 4);
        af[m] = *(const bf16x8*)((const char*)Asm + row * 128 + kb);
      }
#pragma unroll
      for (int nf = 0; nf < 8; ++nf) {
        int row = nf * 16 + c;
        int kb = ((ks * 32 + g * 8) * 2) ^ ((row & 7) << 4);
        bf16x8 bfr = *(const bf16x8*)((const char*)Bsm + row * 128 + kb);
        acc[0][nf] = MFMA16(af[0], bfr, acc[0][nf]);
        acc[1][nf] = MFMA16(af[1], bfr, acc[1][nf]);
      }
    }
    __syncthreads();
  }

  int mbase = mt * 128 + w * 32;
  if (which < 2) {
    // q/k: bias + RoPE (+ QSCALE for q), write bf16 [bh][s][d]
    const float* bias = (which == 0) ? bq : bk;
    uint16_t* outp = (which == 0) ? qws : kws;
    float scl = (which == 0) ? QSCALE : 1.0f;
#pragma unroll
    for (int m = 0; m < 2; ++m)
#pragma unroll
      for (int nf = 0; nf < 4; ++nf) {
        int i = nf * 16 + c;   // rotary index 0..63
        float b1 = bias[h * NDH + i], b2 = bias[h * NDH + 64 + i];
#pragma unroll
        for (int j = 0; j < 4; ++j) {
          int r = mbase + m * 16 + g * 4 + j;   // global M row
          int bb = r >> 11, s = r & (NS - 1);
          float cs = cosT[(s << 6) + i], sn = sinT[(s << 6) + i];
          float x1 = acc[m][nf][j] + b1;
          float x2 = acc[m][nf + 4][j] + b2;
          uint16_t* op = outp + ((size_t)(bb * NH + h) * NS + s) * NDH;
          op[i] = f2bf((x1 * cs - x2 * sn) * scl);
          op[64 + i] = f2bf((x1 * sn + x2 * cs) * scl);
        }
      }
  } else {
    // v: bias, in-LDS transpose (XOR-swizzled, conflict-free), write vt[bh][d][s]
    // tb u16 index = d*128 + (s_local ^ ((d&7)<<3)); pairs (j,j+1) packed b32.
#pragma unroll
    for (int m = 0; m < 2; ++m)
#pragma unroll
      for (int nf = 0; nf < 8; ++nf) {
        int d = nf * 16 + c;
        float bv_ = bv[h * NDH + d];
#pragma unroll
        for (int j = 0; j < 4; j += 2) {
          int sp = w * 32 + m * 16 + g * 4 + j;   // even
          int idx = d * 128 + (sp ^ ((d & 7) << 3));
          uint32_t pk = (uint32_t)f2bf(acc[m][nf][j] + bv_) |
                        ((uint32_t)f2bf(acc[m][nf][j + 1] + bv_) << 16);
          *(uint32_t*)((char*)SM + (size_t)idx * 2) = pk;
        }
      }
    __syncthreads();
    int bb = mt >> 4;
    int s_base = (mt & 15) * 128;
    uint16_t* vtb = vtws + (size_t)(bb * NH + h) * NDH * NS;
#pragma unroll
    for (int it = 0; it < 8; ++it) {
      int flat = it * 256 + t;           // 0..2047
      int d = flat >> 4, chunk = flat & 15;
      int s0 = chunk * 8;
      int idx = d * 128 + (s0 ^ ((d & 7) << 3));
      bf16x8 vv = *(const bf16x8*)((const char*)SM + (size_t)idx * 2);
      *(bf16x8*)(vtb + (size_t)d * NS + s_base + s0) = vv;
    }
  }
}

// ---------------- kernel 2: causal flash attention (paired q-tiles, dbuf K/V) ----------------
// Swapped QK^T: S^T = mfma(K, Q) => each lane owns q-row (lane&15), kv in regs.
// Softmax register-local; q pre-scaled by QSCALE (log2 domain); defer-max THR=8.
// K/V double-buffered: issue next tile's gload_lds BEFORE current compute (T14);
// the __syncthreads vmcnt-drain then retires loads that flew under the compute.
__global__ __launch_bounds__(256, 4) void k_attn(
    const uint16_t* __restrict__ qws, const uint16_t* __restrict__ kws,
    const uint16_t* __restrict__ vtws, float* __restrict__ out) {
  __shared__ alignas(16) uint16_t Ksm[2][64 * 128];  // [kv][d]  rows 256B, swizzled
  __shared__ alignas(16) uint16_t Vsm[2][128 * 64];  // [d][kv]  rows 128B, swizzled
  __shared__ alignas(16) uint16_t Psm[4][16 * 64];   // per-wave [q][kv], swizzled

  int bh = blockIdx.x;                 // 0..31 : b = bh>>4, h = bh&15
  int t = threadIdx.x, w = t >> 6, l = t & 63;
  int g = l >> 4, c = l & 15;
  int bb = bh >> 4, h = bh & 15;

  const uint16_t* Qp = qws + (size_t)bh * NS * NDH;
  const uint16_t* Kp = kws + (size_t)bh * NS * NDH;
  const uint16_t* Vp = vtws + (size_t)bh * NDH * NS;

#define STAGE(bb_, kt_)                                                            \
  do {                                                                             \
    _Pragma("unroll") for (int cc = 0; cc < 4; ++cc) {                             \
      int flat = cc * 256 + t;                                                     \
      int row = flat >> 4, sub = flat & 15;                                        \
      int scol = ((sub ^ (row & 7)) << 3);                                         \
      gload_lds16(&Kp[(size_t)((kt_) * 64 + row) * NDH + scol],                    \
                  (char*)Ksm[bb_] + flat * 16);                                    \
    }                                                                              \
    _Pragma("unroll") for (int cc = 0; cc < 4; ++cc) {                             \
      int flat = cc * 256 + t;                                                     \
      int row = flat >> 3, sub = flat & 7;                                         \
      int scol = ((sub ^ (row & 7)) << 3);                                         \
      gload_lds16(&Vp[(size_t)row * NS + (kt_) * 64 + scol],                       \
                  (char*)Vsm[bb_] + flat * 16);                                    \
    }                                                                              \
  } while (0)

  for (int pass = 0; pass < 2; ++pass) {
    int y64 = pass ? (31 - blockIdx.y) : blockIdx.y;
    int q0 = y64 * 64;
    int r = q0 + w * 16 + c;           // this lane's q row (col of S^T)

    // hoist Q fragments (B-operand: col=lane&15=q row, k = g*8.. within kk*32)
    bf16x8 qf[4];
#pragma unroll
    for (int kk = 0; kk < 4; ++kk)
      qf[kk] = *(const bf16x8*)&Qp[(size_t)r * NDH + kk * 32 + g * 8];

    f32x4 acc_o[8];
    float mreg = -1e30f, lreg = 0.f;
#pragma unroll
    for (int n = 0; n < 8; ++n) acc_o[n] = (f32x4){0.f, 0.f, 0.f, 0.f};

    int nkt = y64 + 1;
    STAGE(0, 0);
    __syncthreads();

    for (int kt = 0; kt < nkt; ++kt) {
      int cur = kt & 1;
      if (kt + 1 < nkt) STAGE(cur ^ 1, kt + 1);   // issue-early: hides under compute

      // S^T = K Q^T : sacc[nf][j] = S[q=r][kv = kt*64 + nf*16 + g*4 + j]
      f32x4 sacc[4];
#pragma unroll
      for (int nf = 0; nf < 4; ++nf) sacc[nf] = (f32x4){0.f, 0.f, 0.f, 0.f};
#pragma unroll
      for (int kk = 0; kk < 4; ++kk) {
#pragma unroll
        for (int nf = 0; nf < 4; ++nf) {
          int row = nf * 16 + c;
          int kb = ((kk * 32 + g * 8) * 2) ^ ((row & 7) << 4);
          bf16x8 kfr = *(const bf16x8*)((const char*)Ksm[cur] + row * 256 + kb);
          sacc[nf] = MFMA16(kfr, qf[kk], sacc[nf]);   // swapped operands
        }
      }

      // causal mask (diagonal tile only)
      if (kt == y64) {
#pragma unroll
        for (int nf = 0; nf < 4; ++nf)
#pragma unroll
          for (int j = 0; j < 4; ++j) {
            int kv = kt * 64 + nf * 16 + g * 4 + j;
            if (kv > r) sacc[nf][j] = -1e30f;
          }
      }

      // register-local row max (this lane's 16 kv values) + 2-shfl combine
      float mx = -1e30f;
#pragma unroll
      for (int nf = 0; nf < 4; ++nf)
        mx = fmaxf(mx, fmaxf(fmaxf(sacc[nf][0], sacc[nf][1]),
                             fmaxf(sacc[nf][2], sacc[nf][3])));
      mx = fmaxf(mx, __shfl_xor(mx, 16));
      mx = fmaxf(mx, __shfl_xor(mx, 32));

      float mnew = mreg;
      if (!__all(mx <= mreg + 8.0f)) {   // defer-max: wave-uniform rescale skip
        mnew = fmaxf(mreg, mx);
        float alpha = exp2f(mreg - mnew);
        mreg = mnew;
        lreg *= alpha;
#pragma unroll
        for (int j = 0; j < 4; ++j) {
          float aj = __shfl(alpha, (l & 48) + g * 4 + j);  // alpha of acc_o's q row
#pragma unroll
          for (int nf = 0; nf < 8; ++nf) acc_o[nf][j] *= aj;
        }
      }

      float rs = 0.f;
#pragma unroll
      for (int nf = 0; nf < 4; ++nf)
#pragma unroll
        for (int j = 0; j < 4; ++j) {
          float p = exp2f(sacc[nf][j] - mnew);
          sacc[nf][j] = p;
          rs += p;
        }
      rs += __shfl_xor(rs, 16);
      rs += __shfl_xor(rs, 32);
      lreg += rs;

      // P -> LDS (packed b32 writes): row = q = c, col = kv
#pragma unroll
      for (int nf = 0; nf < 4; ++nf) {
        uint32_t pk0 = (uint32_t)f2bf(sacc[nf][0]) | ((uint32_t)f2bf(sacc[nf][1]) << 16);
        uint32_t pk1 = (uint32_t)f2bf(sacc[nf][2]) | ((uint32_t)f2bf(sacc[nf][3]) << 16);
        int colb = (nf * 16 + g * 4) * 2;
        char* base = (char*)Psm[w] + c * 128;
        *(uint32_t*)(base + (colb ^ ((c & 7) << 4))) = pk0;
        *(uint32_t*)(base + ((colb + 4) ^ ((c & 7) << 4))) = pk1;
      }

      // O += P V   (contract over kv: 2 k-steps of 32)
#pragma unroll
      for (int kk2 = 0; kk2 < 2; ++kk2) {
        int prow = c;
        int pkb = ((kk2 * 32 + g * 8) * 2) ^ ((prow & 7) << 4);
        bf16x8 pf = *(const bf16x8*)((const char*)Psm[w] + prow * 128 + pkb);
#pragma unroll
        for (int nf = 0; nf < 8; ++nf) {
          int row = nf * 16 + c;
          int kb = ((kk2 * 32 + g * 8) * 2) ^ ((row & 7) << 4);
          bf16x8 vf = *(const bf16x8*)((const char*)Vsm[cur] + row * 128 + kb);
          acc_o[nf] = MFMA16(pf, vf, acc_o[nf]);
        }
      }
      __syncthreads();   // drains vmcnt (staged loads) + gates buffer reuse
    }

    // normalize + store fp32 out[b][s][h*128+d]
#pragma unroll
    for (int j = 0; j < 4; ++j) {
      float lj = __shfl(lreg, (l & 48) + g * 4 + j);
      float inv = 1.0f / lj;
      int s = q0 + w * 16 + g * 4 + j;
      float* op = out + ((size_t)(bb * NS + s)) * NFE + h * NDH;
#pragma unroll
      for (int nf = 0; nf < 8; ++nf) op[nf * 16 + c] = acc_o[nf][j] * inv;
    }
  }
#undef STAGE
}

extern "C" void kernel_launch(void* const* d_in, const int* in_sizes, int n_in,
                              void* d_out, int out_size, void* d_ws, size_t ws_size,
                              hipStream_t stream) {
  const float* in_q = (const float*)d_in[0];
  const float* Wq = (const float*)d_in[1];
  const float* bq = (const float*)d_in[2];
  const float* Wk = (const float*)d_in[3];
  const float* bk = (const float*)d_in[4];
  const float* Wv = (const float*)d_in[5];
  const float* bv = (const float*)d_in[6];
  // d_in[7] = mask (tril causal, hard-coded), d_in[8] = offset
  const int* offp = (const int*)d_in[8];
  float* out = (float*)d_out;

  char* ws = (char*)d_ws;
  const size_t SZ_AQ = (size_t)4096 * 2048 * 2;        // 16 MB
  const size_t SZ_WT = (size_t)3 * 2048 * 2048 * 2;    // 24 MB
  const size_t SZ_TAB = (size_t)2048 * 64 * 4;         // 512 KB
  const size_t SZ_QKV = (size_t)32 * 2048 * 128 * 2;   // 16 MB each
  uint16_t* Aq = (uint16_t*)(ws);
  uint16_t* Wt = (uint16_t*)(ws + SZ_AQ);
  float* cosT = (float*)(ws + SZ_AQ + SZ_WT);
  float* sinT = (float*)(ws + SZ_AQ + SZ_WT + SZ_TAB);
  uint16_t* qws = (uint16_t*)(ws + SZ_AQ + SZ_WT + 2 * SZ_TAB);
  uint16_t* kws = (uint16_t*)(ws + SZ_AQ + SZ_WT + 2 * SZ_TAB + SZ_QKV);
  uint16_t* vtws = (uint16_t*)(ws + SZ_AQ + SZ_WT + 2 * SZ_TAB + 2 * SZ_QKV);

  k_prep<<<11776, 256, 0, stream>>>(in_q, Aq, cosT, sinT, offp, Wq, Wk, Wv, Wt);
  k_gemm_qkv<<<dim3(32, 48), 256, 0, stream>>>(Aq, Wt, bq, bk, bv, cosT, sinT, qws, kws, vtws);
  k_attn<<<dim3(32, 16), 256, 0, stream>>>(qws, kws, vtws, out);
}

// Round 9
// 190.631 us; speedup vs baseline: 1.1957x; 1.0002x over previous
//
#include <hip/hip_runtime.h>
#include <hip/hip_bf16.h>
#include <stdint.h>

// Problem: B=2, S=2048, F=2048, H=16, DH=128, causal, ROPE_BASE=1e4, fp32 I/O.
#define NB 2
#define NS 2048
#define NFE 2048
#define NH 16
#define NDH 128

// softmax scale folded into q (log2 domain): 1/sqrt(128) * log2(e)
#define QSCALE (0.08838834764831845f * 1.4426950408889634f)

typedef __attribute__((ext_vector_type(4))) float f32x4;
typedef __attribute__((ext_vector_type(8))) __bf16 bf16x8;

__device__ __forceinline__ uint16_t f2bf(float f) {
  uint32_t u = __builtin_bit_cast(uint32_t, f);
  return (uint16_t)((u + 0x7fffu + ((u >> 16) & 1u)) >> 16);
}

__device__ __forceinline__ void gload_lds16(const void* g, void* l) {
  __builtin_amdgcn_global_load_lds((const __attribute__((address_space(1))) void*)g,
                                   (__attribute__((address_space(3))) void*)l,
                                   16, 0, 0);
}

#define MFMA16(a, b, c) __builtin_amdgcn_mfma_f32_16x16x32_bf16(a, b, c, 0, 0, 0)

// ---------------- kernel 0: fused prep ----------------
// blocks [0,8192): fp32->bf16 convert of in_q
// blocks [8192,8704): RoPE cos/sin tables [S][64]
// blocks [8704,11776): W transpose+convert [K][N] f32 -> [N][K] bf16 (3 x 1024 tiles)
__global__ void k_prep(const float* __restrict__ x, uint16_t* __restrict__ y,
                       float* __restrict__ cosT, float* __restrict__ sinT,
                       const int* __restrict__ offp,
                       const float* __restrict__ Wq, const float* __restrict__ Wk,
                       const float* __restrict__ Wv, uint16_t* __restrict__ Wt) {
  __shared__ uint16_t tile[64][65];
  int b = blockIdx.x;
  int t = threadIdx.x;
  if (b < 8192) {
    int i = (b * 256 + t) * 4;
    float4 v = *(const float4*)(x + i);
    ushort4 o;
    o.x = f2bf(v.x); o.y = f2bf(v.y); o.z = f2bf(v.z); o.w = f2bf(v.w);
    *(ushort4*)(y + i) = o;
  } else if (b < 8704) {
    int tid = (b - 8192) * 256 + t;   // 0..131071
    int s = tid >> 6, i = tid & 63;
    float off = (float)offp[0];
    float inv = expf(-((float)i / 64.0f) * logf(10000.0f));
    float ang = ((float)s + off) * inv;
    cosT[tid] = cosf(ang);
    sinT[tid] = sinf(ang);
  } else {
    int idx = b - 8704;               // 0..3071
    int which = idx >> 10, rem = idx & 1023;
    int k0 = (rem & 31) * 64, n0 = (rem >> 5) * 64;
    const float* Wsrc = (which == 0) ? Wq : ((which == 1) ? Wk : Wv);
#pragma unroll
    for (int it = 0; it < 4; ++it) {
      int vec = t + it * 256;        // 0..1023
      int r = vec >> 4, c4 = vec & 15;
      float4 v = *(const float4*)&Wsrc[(size_t)(k0 + r) * NFE + n0 + c4 * 4];
      tile[r][c4 * 4 + 0] = f2bf(v.x);
      tile[r][c4 * 4 + 1] = f2bf(v.y);
      tile[r][c4 * 4 + 2] = f2bf(v.z);
      tile[r][c4 * 4 + 3] = f2bf(v.w);
    }
    __syncthreads();
#pragma unroll
    for (int it = 0; it < 4; ++it) {
      int vec = t + it * 256;
      int r = vec >> 4, c4 = vec & 15;   // r = n row, c4*4 = k offset
      ushort4 o;
      o.x = tile[c4 * 4 + 0][r];
      o.y = tile[c4 * 4 + 1][r];
      o.z = tile[c4 * 4 + 2][r];
      o.w = tile[c4 * 4 + 3][r];
      *(ushort4*)&Wt[(size_t)which * NFE * NFE + (size_t)(n0 + r) * NFE + k0 + c4 * 4] = o;
    }
  }
}

// ---------------- kernel 1: QKV GEMM + bias + RoPE (+ fused V-transpose) ----------------
// m97-style 128x128, BK=64; R9 change: 2Mx2N wave layout (wave = 64 rows x 64 cols)
// cuts per-block LDS reads 80->64 KB/K-tile (LDS read pipe was the binding resource:
// 963cy LDS vs 614cy MFMA at 4Mx1N). RoPE pairs kept register-local via interleaved
// column ownership: wave wc owns cols {wc*32..+32} u {wc*32+64..+96};
// col(nf) = wc*32 + (nf&1)*16 + (nf>>1)*64, pair (i,i+64) = acc[m][nf] / acc[m][nf+2].
__global__ __launch_bounds__(256, 2) void k_gemm_qkv(
    const uint16_t* __restrict__ A, const uint16_t* __restrict__ Wt,
    const float* __restrict__ bq, const float* __restrict__ bk, const float* __restrict__ bv,
    const float* __restrict__ cosT, const float* __restrict__ sinT,
    uint16_t* __restrict__ qws, uint16_t* __restrict__ kws, uint16_t* __restrict__ vtws) {
  __shared__ alignas(16) uint16_t SM[2 * 128 * 64];   // Asm = SM, Bsm = SM+8192
  uint16_t* Asm = SM;
  uint16_t* Bsm = SM + 8192;
  int mt = blockIdx.x;                 // 0..31
  int nt = blockIdx.y;                 // 0..47
  int which = nt >> 4, h = nt & 15;
  const uint16_t* Bsrc = Wt + (size_t)which * NFE * NFE + (size_t)h * NDH * NFE;
  const uint16_t* Arow = A + (size_t)mt * 128 * NFE;
  int t = threadIdx.x, w = t >> 6, l = t & 63;
  int g = l >> 4, c = l & 15;
  int wr = w >> 1, wc = w & 1;

  f32x4 acc[4][4];
#pragma unroll
  for (int m = 0; m < 4; ++m)
#pragma unroll
    for (int n = 0; n < 4; ++n) acc[m][n] = (f32x4){0.f, 0.f, 0.f, 0.f};

  for (int kt = 0; kt < NFE / 64; ++kt) {
    int k0 = kt * 64;
#pragma unroll
    for (int cc = 0; cc < 4; ++cc) {
      int flat = cc * 256 + t;         // row = flat>>3 (128B rows), sub = flat&7
      int row = flat >> 3, sub = flat & 7;
      int scol = ((sub ^ (row & 7)) << 3) + k0;
      gload_lds16(&Arow[(size_t)row * NFE + scol], (char*)Asm + flat * 16);
    }
#pragma unroll
    for (int cc = 0; cc < 4; ++cc) {
      int flat = cc * 256 + t;
      int row = flat >> 3, sub = flat & 7;
      int scol = ((sub ^ (row & 7)) << 3) + k0;
      gload_lds16(&Bsrc[(size_t)row * NFE + scol], (char*)Bsm + flat * 16);
    }
    __syncthreads();
#pragma unroll
    for (int ks = 0; ks < 2; ++ks) {
      bf16x8 af[4], bf[4];
#pragma unroll
      for (int m = 0; m < 4; ++m) {
        int row = wr * 64 + m * 16 + c;
        int kb = ((ks * 32 + g * 8) * 2) ^ ((row & 7) << 4);
        af[m] = *(const bf16x8*)((const char*)Asm + row * 128 + kb);
      }
#pragma unroll
      for (int nf = 0; nf < 4; ++nf) {
        int row = wc * 32 + (nf & 1) * 16 + (nf >> 1) * 64 + c;
        int kb = ((ks * 32 + g * 8) * 2) ^ ((row & 7) << 4);
        bf[nf] = *(const bf16x8*)((const char*)Bsm + row * 128 + kb);
      }
#pragma unroll
      for (int m = 0; m < 4; ++m)
#pragma unroll
        for (int nf = 0; nf < 4; ++nf)
          acc[m][nf] = MFMA16(af[m], bf[nf], acc[m][nf]);
    }
    __syncthreads();
  }

  int mbase = mt * 128 + wr * 64;
  if (which < 2) {
    // q/k: bias + RoPE (+ QSCALE for q), write bf16 [bh][s][d]
    const float* bias = (which == 0) ? bq : bk;
    uint16_t* outp = (which == 0) ? qws : kws;
    float scl = (which == 0) ? QSCALE : 1.0f;
#pragma unroll
    for (int m = 0; m < 4; ++m)
#pragma unroll
      for (int np = 0; np < 2; ++np) {
        int i = wc * 32 + np * 16 + c;   // rotary index 0..63
        float b1 = bias[h * NDH + i], b2 = bias[h * NDH + 64 + i];
#pragma unroll
        for (int j = 0; j < 4; ++j) {
          int r = mbase + m * 16 + g * 4 + j;   // global M row
          int bb = r >> 11, s = r & (NS - 1);
          float cs = cosT[(s << 6) + i], sn = sinT[(s << 6) + i];
          float x1 = acc[m][np][j] + b1;       // d = i
          float x2 = acc[m][np + 2][j] + b2;   // d = i + 64
          uint16_t* op = outp + ((size_t)(bb * NH + h) * NS + s) * NDH;
          op[i] = f2bf((x1 * cs - x2 * sn) * scl);
          op[64 + i] = f2bf((x1 * sn + x2 * cs) * scl);
        }
      }
  } else {
    // v: bias, in-LDS transpose (XOR-swizzled), write vt[bh][d][s]
#pragma unroll
    for (int m = 0; m < 4; ++m)
#pragma unroll
      for (int nf = 0; nf < 4; ++nf) {
        int d = wc * 32 + (nf & 1) * 16 + (nf >> 1) * 64 + c;
        float bv_ = bv[h * NDH + d];
#pragma unroll
        for (int j = 0; j < 4; j += 2) {
          int sp = wr * 64 + m * 16 + g * 4 + j;   // even
          int idx = d * 128 + (sp ^ ((d & 7) << 3));
          uint32_t pk = (uint32_t)f2bf(acc[m][nf][j] + bv_) |
                        ((uint32_t)f2bf(acc[m][nf][j + 1] + bv_) << 16);
          *(uint32_t*)((char*)SM + (size_t)idx * 2) = pk;
        }
      }
    __syncthreads();
    int bb = mt >> 4;
    int s_base = (mt & 15) * 128;
    uint16_t* vtb = vtws + (size_t)(bb * NH + h) * NDH * NS;
#pragma unroll
    for (int it = 0; it < 8; ++it) {
      int flat = it * 256 + t;           // 0..2047
      int d = flat >> 4, chunk = flat & 15;
      int s0 = chunk * 8;
      int idx = d * 128 + (s0 ^ ((d & 7) << 3));
      bf16x8 vv = *(const bf16x8*)((const char*)SM + (size_t)idx * 2);
      *(bf16x8*)(vtb + (size_t)d * NS + s_base + s0) = vv;
    }
  }
}

// ---------------- kernel 2: causal flash attention (paired q-tiles, dbuf K/V) ----------------
// Swapped QK^T: S^T = mfma(K, Q) => each lane owns q-row (lane&15), kv in regs.
// Softmax register-local; q pre-scaled by QSCALE (log2 domain); defer-max THR=8.
// K/V double-buffered: issue next tile's gload_lds BEFORE current compute (T14).
__global__ __launch_bounds__(256, 4) void k_attn(
    const uint16_t* __restrict__ qws, const uint16_t* __restrict__ kws,
    const uint16_t* __restrict__ vtws, float* __restrict__ out) {
  __shared__ alignas(16) uint16_t Ksm[2][64 * 128];  // [kv][d]  rows 256B, swizzled
  __shared__ alignas(16) uint16_t Vsm[2][128 * 64];  // [d][kv]  rows 128B, swizzled
  __shared__ alignas(16) uint16_t Psm[4][16 * 64];   // per-wave [q][kv], swizzled

  int bh = blockIdx.x;                 // 0..31 : b = bh>>4, h = bh&15
  int t = threadIdx.x, w = t >> 6, l = t & 63;
  int g = l >> 4, c = l & 15;
  int bb = bh >> 4, h = bh & 15;

  const uint16_t* Qp = qws + (size_t)bh * NS * NDH;
  const uint16_t* Kp = kws + (size_t)bh * NS * NDH;
  const uint16_t* Vp = vtws + (size_t)bh * NDH * NS;

#define STAGE(bb_, kt_)                                                            \
  do {                                                                             \
    _Pragma("unroll") for (int cc = 0; cc < 4; ++cc) {                             \
      int flat = cc * 256 + t;                                                     \
      int row = flat >> 4, sub = flat & 15;                                        \
      int scol = ((sub ^ (row & 7)) << 3);                                         \
      gload_lds16(&Kp[(size_t)((kt_) * 64 + row) * NDH + scol],                    \
                  (char*)Ksm[bb_] + flat * 16);                                    \
    }                                                                              \
    _Pragma("unroll") for (int cc = 0; cc < 4; ++cc) {                             \
      int flat = cc * 256 + t;                                                     \
      int row = flat >> 3, sub = flat & 7;                                         \
      int scol = ((sub ^ (row & 7)) << 3);                                         \
      gload_lds16(&Vp[(size_t)row * NS + (kt_) * 64 + scol],                       \
                  (char*)Vsm[bb_] + flat * 16);                                    \
    }                                                                              \
  } while (0)

  for (int pass = 0; pass < 2; ++pass) {
    int y64 = pass ? (31 - blockIdx.y) : blockIdx.y;
    int q0 = y64 * 64;
    int r = q0 + w * 16 + c;           // this lane's q row (col of S^T)

    // hoist Q fragments (B-operand: col=lane&15=q row, k = g*8.. within kk*32)
    bf16x8 qf[4];
#pragma unroll
    for (int kk = 0; kk < 4; ++kk)
      qf[kk] = *(const bf16x8*)&Qp[(size_t)r * NDH + kk * 32 + g * 8];

    f32x4 acc_o[8];
    float mreg = -1e30f, lreg = 0.f;
#pragma unroll
    for (int n = 0; n < 8; ++n) acc_o[n] = (f32x4){0.f, 0.f, 0.f, 0.f};

    int nkt = y64 + 1;
    STAGE(0, 0);
    __syncthreads();

    for (int kt = 0; kt < nkt; ++kt) {
      int cur = kt & 1;
      if (kt + 1 < nkt) STAGE(cur ^ 1, kt + 1);   // issue-early: hides under compute

      // S^T = K Q^T : sacc[nf][j] = S[q=r][kv = kt*64 + nf*16 + g*4 + j]
      f32x4 sacc[4];
#pragma unroll
      for (int nf = 0; nf < 4; ++nf) sacc[nf] = (f32x4){0.f, 0.f, 0.f, 0.f};
#pragma unroll
      for (int kk = 0; kk < 4; ++kk) {
#pragma unroll
        for (int nf = 0; nf < 4; ++nf) {
          int row = nf * 16 + c;
          int kb = ((kk * 32 + g * 8) * 2) ^ ((row & 7) << 4);
          bf16x8 kfr = *(const bf16x8*)((const char*)Ksm[cur] + row * 256 + kb);
          sacc[nf] = MFMA16(kfr, qf[kk], sacc[nf]);   // swapped operands
        }
      }

      // causal mask (diagonal tile only)
      if (kt == y64) {
#pragma unroll
        for (int nf = 0; nf < 4; ++nf)
#pragma unroll
          for (int j = 0; j < 4; ++j) {
            int kv = kt * 64 + nf * 16 + g * 4 + j;
            if (kv > r) sacc[nf][j] = -1e30f;
          }
      }

      // register-local row max (this lane's 16 kv values) + 2-shfl combine
      float mx = -1e30f;
#pragma unroll
      for (int nf = 0; nf < 4; ++nf)
        mx = fmaxf(mx, fmaxf(fmaxf(sacc[nf][0], sacc[nf][1]),
                             fmaxf(sacc[nf][2], sacc[nf][3])));
      mx = fmaxf(mx, __shfl_xor(mx, 16));
      mx = fmaxf(mx, __shfl_xor(mx, 32));

      float mnew = mreg;
      if (!__all(mx <= mreg + 8.0f)) {   // defer-max: wave-uniform rescale skip
        mnew = fmaxf(mreg, mx);
        float alpha = exp2f(mreg - mnew);
        mreg = mnew;
        lreg *= alpha;
#pragma unroll
        for (int j = 0; j < 4; ++j) {
          float aj = __shfl(alpha, (l & 48) + g * 4 + j);  // alpha of acc_o's q row
#pragma unroll
          for (int nf = 0; nf < 8; ++nf) acc_o[nf][j] *= aj;
        }
      }

      float rs = 0.f;
#pragma unroll
      for (int nf = 0; nf < 4; ++nf)
#pragma unroll
        for (int j = 0; j < 4; ++j) {
          float p = exp2f(sacc[nf][j] - mnew);
          sacc[nf][j] = p;
          rs += p;
        }
      rs += __shfl_xor(rs, 16);
      rs += __shfl_xor(rs, 32);
      lreg += rs;

      // P -> LDS (packed b32 writes): row = q = c, col = kv
#pragma unroll
      for (int nf = 0; nf < 4; ++nf) {
        uint32_t pk0 = (uint32_t)f2bf(sacc[nf][0]) | ((uint32_t)f2bf(sacc[nf][1]) << 16);
        uint32_t pk1 = (uint32_t)f2bf(sacc[nf][2]) | ((uint32_t)f2bf(sacc[nf][3]) << 16);
        int colb = (nf * 16 + g * 4) * 2;
        char* base = (char*)Psm[w] + c * 128;
        *(uint32_t*)(base + (colb ^ ((c & 7) << 4))) = pk0;
        *(uint32_t*)(base + ((colb + 4) ^ ((c & 7) << 4))) = pk1;
      }

      // O += P V   (contract over kv: 2 k-steps of 32)
#pragma unroll
      for (int kk2 = 0; kk2 < 2; ++kk2) {
        int prow = c;
        int pkb = ((kk2 * 32 + g * 8) * 2) ^ ((prow & 7) << 4);
        bf16x8 pf = *(const bf16x8*)((const char*)Psm[w] + prow * 128 + pkb);
#pragma unroll
        for (int nf = 0; nf < 8; ++nf) {
          int row = nf * 16 + c;
          int kb = ((kk2 * 32 + g * 8) * 2) ^ ((row & 7) << 4);
          bf16x8 vf = *(const bf16x8*)((const char*)Vsm[cur] + row * 128 + kb);
          acc_o[nf] = MFMA16(pf, vf, acc_o[nf]);
        }
      }
      __syncthreads();   // drains vmcnt (staged loads) + gates buffer reuse
    }

    // normalize + store fp32 out[b][s][h*128+d]
#pragma unroll
    for (int j = 0; j < 4; ++j) {
      float lj = __shfl(lreg, (l & 48) + g * 4 + j);
      float inv = 1.0f / lj;
      int s = q0 + w * 16 + g * 4 + j;
      float* op = out + ((size_t)(bb * NS + s)) * NFE + h * NDH;
#pragma unroll
      for (int nf = 0; nf < 8; ++nf) op[nf * 16 + c] = acc_o[nf][j] * inv;
    }
  }
#undef STAGE
}

extern "C" void kernel_launch(void* const* d_in, const int* in_sizes, int n_in,
                              void* d_out, int out_size, void* d_ws, size_t ws_size,
                              hipStream_t stream) {
  const float* in_q = (const float*)d_in[0];
  const float* Wq = (const float*)d_in[1];
  const float* bq = (const float*)d_in[2];
  const float* Wk = (const float*)d_in[3];
  const float* bk = (const float*)d_in[4];
  const float* Wv = (const float*)d_in[5];
  const float* bv = (const float*)d_in[6];
  // d_in[7] = mask (tril causal, hard-coded), d_in[8] = offset
  const int* offp = (const int*)d_in[8];
  float* out = (float*)d_out;

  char* ws = (char*)d_ws;
  const size_t SZ_AQ = (size_t)4096 * 2048 * 2;        // 16 MB
  const size_t SZ_WT = (size_t)3 * 2048 * 2048 * 2;    // 24 MB
  const size_t SZ_TAB = (size_t)2048 * 64 * 4;         // 512 KB
  const size_t SZ_QKV = (size_t)32 * 2048 * 128 * 2;   // 16 MB each
  uint16_t* Aq = (uint16_t*)(ws);
  uint16_t* Wt = (uint16_t*)(ws + SZ_AQ);
  float* cosT = (float*)(ws + SZ_AQ + SZ_WT);
  float* sinT = (float*)(ws + SZ_AQ + SZ_WT + SZ_TAB);
  uint16_t* qws = (uint16_t*)(ws + SZ_AQ + SZ_WT + 2 * SZ_TAB);
  uint16_t* kws = (uint16_t*)(ws + SZ_AQ + SZ_WT + 2 * SZ_TAB + SZ_QKV);
  uint16_t* vtws = (uint16_t*)(ws + SZ_AQ + SZ_WT + 2 * SZ_TAB + 2 * SZ_QKV);

  k_prep<<<11776, 256, 0, stream>>>(in_q, Aq, cosT, sinT, offp, Wq, Wk, Wv, Wt);
  k_gemm_qkv<<<dim3(32, 48), 256, 0, stream>>>(Aq, Wt, bq, bk, bv, cosT, sinT, qws, kws, vtws);
  k_attn<<<dim3(32, 16), 256, 0, stream>>>(qws, kws, vtws, out);
}

// Round 10
// 186.189 us; speedup vs baseline: 1.2242x; 1.0239x over previous
//
#include <hip/hip_runtime.h>
#include <hip/hip_bf16.h>
#include <stdint.h>

// Problem: B=2, S=2048, F=2048, H=16, DH=128, causal, ROPE_BASE=1e4, fp32 I/O.
#define NB 2
#define NS 2048
#define NFE 2048
#define NH 16
#define NDH 128

// softmax scale folded into q (log2 domain): 1/sqrt(128) * log2(e)
#define QSCALE (0.08838834764831845f * 1.4426950408889634f)

typedef __attribute__((ext_vector_type(4))) float f32x4;
typedef __attribute__((ext_vector_type(8))) __bf16 bf16x8;

__device__ __forceinline__ uint16_t f2bf(float f) {
  uint32_t u = __builtin_bit_cast(uint32_t, f);
  return (uint16_t)((u + 0x7fffu + ((u >> 16) & 1u)) >> 16);
}

__device__ __forceinline__ void gload_lds16(const void* g, void* l) {
  __builtin_amdgcn_global_load_lds((const __attribute__((address_space(1))) void*)g,
                                   (__attribute__((address_space(3))) void*)l,
                                   16, 0, 0);
}

#define MFMA16(a, b, c) __builtin_amdgcn_mfma_f32_16x16x32_bf16(a, b, c, 0, 0, 0)

// ---------------- kernel 0: fused prep ----------------
// blocks [0,8192): fp32->bf16 convert of in_q
// blocks [8192,8704): RoPE cos/sin tables [S][64]
// blocks [8704,11776): W transpose+convert [K][N] f32 -> [N][K] bf16 (3 x 1024 tiles)
__global__ void k_prep(const float* __restrict__ x, uint16_t* __restrict__ y,
                       float* __restrict__ cosT, float* __restrict__ sinT,
                       const int* __restrict__ offp,
                       const float* __restrict__ Wq, const float* __restrict__ Wk,
                       const float* __restrict__ Wv, uint16_t* __restrict__ Wt) {
  __shared__ uint16_t tile[64][65];
  int b = blockIdx.x;
  int t = threadIdx.x;
  if (b < 8192) {
    int i = (b * 256 + t) * 4;
    float4 v = *(const float4*)(x + i);
    ushort4 o;
    o.x = f2bf(v.x); o.y = f2bf(v.y); o.z = f2bf(v.z); o.w = f2bf(v.w);
    *(ushort4*)(y + i) = o;
  } else if (b < 8704) {
    int tid = (b - 8192) * 256 + t;   // 0..131071
    int s = tid >> 6, i = tid & 63;
    float off = (float)offp[0];
    float inv = expf(-((float)i / 64.0f) * logf(10000.0f));
    float ang = ((float)s + off) * inv;
    cosT[tid] = cosf(ang);
    sinT[tid] = sinf(ang);
  } else {
    int idx = b - 8704;               // 0..3071
    int which = idx >> 10, rem = idx & 1023;
    int k0 = (rem & 31) * 64, n0 = (rem >> 5) * 64;
    const float* Wsrc = (which == 0) ? Wq : ((which == 1) ? Wk : Wv);
#pragma unroll
    for (int it = 0; it < 4; ++it) {
      int vec = t + it * 256;        // 0..1023
      int r = vec >> 4, c4 = vec & 15;
      float4 v = *(const float4*)&Wsrc[(size_t)(k0 + r) * NFE + n0 + c4 * 4];
      tile[r][c4 * 4 + 0] = f2bf(v.x);
      tile[r][c4 * 4 + 1] = f2bf(v.y);
      tile[r][c4 * 4 + 2] = f2bf(v.z);
      tile[r][c4 * 4 + 3] = f2bf(v.w);
    }
    __syncthreads();
#pragma unroll
    for (int it = 0; it < 4; ++it) {
      int vec = t + it * 256;
      int r = vec >> 4, c4 = vec & 15;   // r = n row, c4*4 = k offset
      ushort4 o;
      o.x = tile[c4 * 4 + 0][r];
      o.y = tile[c4 * 4 + 1][r];
      o.z = tile[c4 * 4 + 2][r];
      o.w = tile[c4 * 4 + 3][r];
      *(ushort4*)&Wt[(size_t)which * NFE * NFE + (size_t)(n0 + r) * NFE + k0 + c4 * 4] = o;
    }
  }
}

// ---------------- kernel 1: QKV GEMM + bias + RoPE (+ fused V-transpose) ----------------
// m97-style 128x128, BK=64, 2Mx2N waves (R9). At the documented ~980 TF structural
// ceiling (barrier drain); m201-class schedules failed to reproduce (R4/R5), BK=128
// ruled out by m132 occupancy precedent. Parked.
__global__ __launch_bounds__(256, 2) void k_gemm_qkv(
    const uint16_t* __restrict__ A, const uint16_t* __restrict__ Wt,
    const float* __restrict__ bq, const float* __restrict__ bk, const float* __restrict__ bv,
    const float* __restrict__ cosT, const float* __restrict__ sinT,
    uint16_t* __restrict__ qws, uint16_t* __restrict__ kws, uint16_t* __restrict__ vtws) {
  __shared__ alignas(16) uint16_t SM[2 * 128 * 64];   // Asm = SM, Bsm = SM+8192
  uint16_t* Asm = SM;
  uint16_t* Bsm = SM + 8192;
  int mt = blockIdx.x;                 // 0..31
  int nt = blockIdx.y;                 // 0..47
  int which = nt >> 4, h = nt & 15;
  const uint16_t* Bsrc = Wt + (size_t)which * NFE * NFE + (size_t)h * NDH * NFE;
  const uint16_t* Arow = A + (size_t)mt * 128 * NFE;
  int t = threadIdx.x, w = t >> 6, l = t & 63;
  int g = l >> 4, c = l & 15;
  int wr = w >> 1, wc = w & 1;

  f32x4 acc[4][4];
#pragma unroll
  for (int m = 0; m < 4; ++m)
#pragma unroll
    for (int n = 0; n < 4; ++n) acc[m][n] = (f32x4){0.f, 0.f, 0.f, 0.f};

  for (int kt = 0; kt < NFE / 64; ++kt) {
    int k0 = kt * 64;
#pragma unroll
    for (int cc = 0; cc < 4; ++cc) {
      int flat = cc * 256 + t;         // row = flat>>3 (128B rows), sub = flat&7
      int row = flat >> 3, sub = flat & 7;
      int scol = ((sub ^ (row & 7)) << 3) + k0;
      gload_lds16(&Arow[(size_t)row * NFE + scol], (char*)Asm + flat * 16);
    }
#pragma unroll
    for (int cc = 0; cc < 4; ++cc) {
      int flat = cc * 256 + t;
      int row = flat >> 3, sub = flat & 7;
      int scol = ((sub ^ (row & 7)) << 3) + k0;
      gload_lds16(&Bsrc[(size_t)row * NFE + scol], (char*)Bsm + flat * 16);
    }
    __syncthreads();
#pragma unroll
    for (int ks = 0; ks < 2; ++ks) {
      bf16x8 af[4], bf[4];
#pragma unroll
      for (int m = 0; m < 4; ++m) {
        int row = wr * 64 + m * 16 + c;
        int kb = ((ks * 32 + g * 8) * 2) ^ ((row & 7) << 4);
        af[m] = *(const bf16x8*)((const char*)Asm + row * 128 + kb);
      }
#pragma unroll
      for (int nf = 0; nf < 4; ++nf) {
        int row = wc * 32 + (nf & 1) * 16 + (nf >> 1) * 64 + c;
        int kb = ((ks * 32 + g * 8) * 2) ^ ((row & 7) << 4);
        bf[nf] = *(const bf16x8*)((const char*)Bsm + row * 128 + kb);
      }
#pragma unroll
      for (int m = 0; m < 4; ++m)
#pragma unroll
        for (int nf = 0; nf < 4; ++nf)
          acc[m][nf] = MFMA16(af[m], bf[nf], acc[m][nf]);
    }
    __syncthreads();
  }

  int mbase = mt * 128 + wr * 64;
  if (which < 2) {
    // q/k: bias + RoPE (+ QSCALE for q), write bf16 [bh][s][d]
    const float* bias = (which == 0) ? bq : bk;
    uint16_t* outp = (which == 0) ? qws : kws;
    float scl = (which == 0) ? QSCALE : 1.0f;
#pragma unroll
    for (int m = 0; m < 4; ++m)
#pragma unroll
      for (int np = 0; np < 2; ++np) {
        int i = wc * 32 + np * 16 + c;   // rotary index 0..63
        float b1 = bias[h * NDH + i], b2 = bias[h * NDH + 64 + i];
#pragma unroll
        for (int j = 0; j < 4; ++j) {
          int r = mbase + m * 16 + g * 4 + j;   // global M row
          int bb = r >> 11, s = r & (NS - 1);
          float cs = cosT[(s << 6) + i], sn = sinT[(s << 6) + i];
          float x1 = acc[m][np][j] + b1;       // d = i
          float x2 = acc[m][np + 2][j] + b2;   // d = i + 64
          uint16_t* op = outp + ((size_t)(bb * NH + h) * NS + s) * NDH;
          op[i] = f2bf((x1 * cs - x2 * sn) * scl);
          op[64 + i] = f2bf((x1 * sn + x2 * cs) * scl);
        }
      }
  } else {
    // v: bias, in-LDS transpose (XOR-swizzled), write vt[bh][d][s]
#pragma unroll
    for (int m = 0; m < 4; ++m)
#pragma unroll
      for (int nf = 0; nf < 4; ++nf) {
        int d = wc * 32 + (nf & 1) * 16 + (nf >> 1) * 64 + c;
        float bv_ = bv[h * NDH + d];
#pragma unroll
        for (int j = 0; j < 4; j += 2) {
          int sp = wr * 64 + m * 16 + g * 4 + j;   // even
          int idx = d * 128 + (sp ^ ((d & 7) << 3));
          uint32_t pk = (uint32_t)f2bf(acc[m][nf][j] + bv_) |
                        ((uint32_t)f2bf(acc[m][nf][j + 1] + bv_) << 16);
          *(uint32_t*)((char*)SM + (size_t)idx * 2) = pk;
        }
      }
    __syncthreads();
    int bb = mt >> 4;
    int s_base = (mt & 15) * 128;
    uint16_t* vtb = vtws + (size_t)(bb * NH + h) * NDH * NS;
#pragma unroll
    for (int it = 0; it < 8; ++it) {
      int flat = it * 256 + t;           // 0..2047
      int d = flat >> 4, chunk = flat & 15;
      int s0 = chunk * 8;
      int idx = d * 128 + (s0 ^ ((d & 7) << 3));
      bf16x8 vv = *(const bf16x8*)((const char*)SM + (size_t)idx * 2);
      *(bf16x8*)(vtb + (size_t)d * NS + s_base + s0) = vv;
    }
  }
}

// ---------------- kernel 2: causal flash attention (merged paired q-tiles) ----------------
// R10: the two causal-paired q-tiles (y, 31-y) share ONE k-sweep: K/V staged once for
// kt=0..(31-y) (17..32 stagings vs 33), both tiles compute from the same LDS buffers
// (A active for kt<=y). Compute stays 33 tile-units/block (balanced); barriers drop
// ~2x; T14 hiding improves (2x compute per staged tile). State doubled -> lb(256,2)
// (LDS 72KB caps at 2 blocks/CU anyway).
__global__ __launch_bounds__(256, 2) void k_attn(
    const uint16_t* __restrict__ qws, const uint16_t* __restrict__ kws,
    const uint16_t* __restrict__ vtws, float* __restrict__ out) {
  __shared__ alignas(16) uint16_t Ksm[2][64 * 128];  // [kv][d]  rows 256B, swizzled
  __shared__ alignas(16) uint16_t Vsm[2][128 * 64];  // [d][kv]  rows 128B, swizzled
  __shared__ alignas(16) uint16_t Psm[4][16 * 64];   // per-wave [q][kv], swizzled

  int bh = blockIdx.x;                 // 0..31 : b = bh>>4, h = bh&15
  int t = threadIdx.x, w = t >> 6, l = t & 63;
  int g = l >> 4, c = l & 15;
  int bb = bh >> 4, h = bh & 15;

  const uint16_t* Qp = qws + (size_t)bh * NS * NDH;
  const uint16_t* Kp = kws + (size_t)bh * NS * NDH;
  const uint16_t* Vp = vtws + (size_t)bh * NDH * NS;

#define STAGE(bb_, kt_)                                                            \
  do {                                                                             \
    _Pragma("unroll") for (int cc = 0; cc < 4; ++cc) {                             \
      int flat = cc * 256 + t;                                                     \
      int row = flat >> 4, sub = flat & 15;                                        \
      int scol = ((sub ^ (row & 7)) << 3);                                         \
      gload_lds16(&Kp[(size_t)((kt_) * 64 + row) * NDH + scol],                    \
                  (char*)Ksm[bb_] + flat * 16);                                    \
    }                                                                              \
    _Pragma("unroll") for (int cc = 0; cc < 4; ++cc) {                             \
      int flat = cc * 256 + t;                                                     \
      int row = flat >> 3, sub = flat & 7;                                         \
      int scol = ((sub ^ (row & 7)) << 3);                                         \
      gload_lds16(&Vp[(size_t)row * NS + (kt_) * 64 + scol],                       \
                  (char*)Vsm[bb_] + flat * 16);                                    \
    }                                                                              \
  } while (0)

// one q-tile's per-k-tile body: QK^T (swapped), mask@diag, online softmax, P->LDS, PV
#define TILEBODY(qf_, acc_, mreg_, lreg_, y64_, r_)                                \
  do {                                                                             \
    f32x4 sacc[4];                                                                 \
    _Pragma("unroll") for (int nf = 0; nf < 4; ++nf)                               \
      sacc[nf] = (f32x4){0.f, 0.f, 0.f, 0.f};                                      \
    _Pragma("unroll") for (int kk = 0; kk < 4; ++kk) {                             \
      _Pragma("unroll") for (int nf = 0; nf < 4; ++nf) {                           \
        int row = nf * 16 + c;                                                     \
        int kb = ((kk * 32 + g * 8) * 2) ^ ((row & 7) << 4);                       \
        bf16x8 kfr = *(const bf16x8*)((const char*)Ksm[cur] + row * 256 + kb);     \
        sacc[nf] = MFMA16(kfr, qf_[kk], sacc[nf]);                                 \
      }                                                                            \
    }                                                                              \
    if (kt == (y64_)) {                                                            \
      _Pragma("unroll") for (int nf = 0; nf < 4; ++nf)                             \
        _Pragma("unroll") for (int j = 0; j < 4; ++j) {                            \
          int kv = kt * 64 + nf * 16 + g * 4 + j;                                  \
          if (kv > (r_)) sacc[nf][j] = -1e30f;                                     \
        }                                                                          \
    }                                                                              \
    float mx = -1e30f;                                                             \
    _Pragma("unroll") for (int nf = 0; nf < 4; ++nf)                               \
      mx = fmaxf(mx, fmaxf(fmaxf(sacc[nf][0], sacc[nf][1]),                        \
                           fmaxf(sacc[nf][2], sacc[nf][3])));                      \
    mx = fmaxf(mx, __shfl_xor(mx, 16));                                            \
    mx = fmaxf(mx, __shfl_xor(mx, 32));                                            \
    float mnew = mreg_;                                                            \
    if (!__all(mx <= mreg_ + 8.0f)) {                                              \
      mnew = fmaxf(mreg_, mx);                                                     \
      float alpha = exp2f(mreg_ - mnew);                                           \
      mreg_ = mnew;                                                                \
      lreg_ *= alpha;                                                              \
      _Pragma("unroll") for (int j = 0; j < 4; ++j) {                              \
        float aj = __shfl(alpha, (l & 48) + g * 4 + j);                            \
        _Pragma("unroll") for (int nf = 0; nf < 8; ++nf) acc_[nf][j] *= aj;        \
      }                                                                            \
    }                                                                              \
    float rs = 0.f;                                                                \
    _Pragma("unroll") for (int nf = 0; nf < 4; ++nf)                               \
      _Pragma("unroll") for (int j = 0; j < 4; ++j) {                              \
        float p = exp2f(sacc[nf][j] - mnew);                                       \
        sacc[nf][j] = p;                                                           \
        rs += p;                                                                   \
      }                                                                            \
    rs += __shfl_xor(rs, 16);                                                      \
    rs += __shfl_xor(rs, 32);                                                      \
    lreg_ += rs;                                                                   \
    _Pragma("unroll") for (int nf = 0; nf < 4; ++nf) {                             \
      uint32_t pk0 = (uint32_t)f2bf(sacc[nf][0]) | ((uint32_t)f2bf(sacc[nf][1]) << 16); \
      uint32_t pk1 = (uint32_t)f2bf(sacc[nf][2]) | ((uint32_t)f2bf(sacc[nf][3]) << 16); \
      int colb = (nf * 16 + g * 4) * 2;                                            \
      char* base = (char*)Psm[w] + c * 128;                                        \
      *(uint32_t*)(base + (colb ^ ((c & 7) << 4))) = pk0;                          \
      *(uint32_t*)(base + ((colb + 4) ^ ((c & 7) << 4))) = pk1;                    \
    }                                                                              \
    _Pragma("unroll") for (int kk2 = 0; kk2 < 2; ++kk2) {                          \
      int pkb = ((kk2 * 32 + g * 8) * 2) ^ ((c & 7) << 4);                         \
      bf16x8 pf = *(const bf16x8*)((const char*)Psm[w] + c * 128 + pkb);           \
      _Pragma("unroll") for (int nf = 0; nf < 8; ++nf) {                           \
        int row = nf * 16 + c;                                                     \
        int kb = ((kk2 * 32 + g * 8) * 2) ^ ((row & 7) << 4);                      \
        bf16x8 vf = *(const bf16x8*)((const char*)Vsm[cur] + row * 128 + kb);      \
        acc_[nf] = MFMA16(pf, vf, acc_[nf]);                                       \
      }                                                                            \
    }                                                                              \
  } while (0)

  int y64A = blockIdx.y;               // 0..15
  int y64B = 31 - y64A;                // 16..31
  int rA = y64A * 64 + w * 16 + c;     // lane's q row for tile A
  int rB = y64B * 64 + w * 16 + c;     // lane's q row for tile B

  // hoist Q fragments for both tiles
  bf16x8 qfA[4], qfB[4];
#pragma unroll
  for (int kk = 0; kk < 4; ++kk) {
    qfA[kk] = *(const bf16x8*)&Qp[(size_t)rA * NDH + kk * 32 + g * 8];
    qfB[kk] = *(const bf16x8*)&Qp[(size_t)rB * NDH + kk * 32 + g * 8];
  }

  f32x4 accA[8], accB[8];
  float mA = -1e30f, lA = 0.f, mB = -1e30f, lB = 0.f;
#pragma unroll
  for (int n = 0; n < 8; ++n) {
    accA[n] = (f32x4){0.f, 0.f, 0.f, 0.f};
    accB[n] = (f32x4){0.f, 0.f, 0.f, 0.f};
  }

  STAGE(0, 0);
  __syncthreads();

  int ktB = y64B;                      // last k-tile (B's diagonal)
  for (int kt = 0; kt <= ktB; ++kt) {
    int cur = kt & 1;
    if (kt < ktB) STAGE(cur ^ 1, kt + 1);   // issue-early: hides under both computes
    if (kt <= y64A) TILEBODY(qfA, accA, mA, lA, y64A, rA);
    TILEBODY(qfB, accB, mB, lB, y64B, rB);
    __syncthreads();   // drains vmcnt (staged loads) + gates buffer reuse
  }

  // normalize + store fp32 out[b][s][h*128+d] for both tiles
#pragma unroll
  for (int j = 0; j < 4; ++j) {
    float lj = __shfl(lA, (l & 48) + g * 4 + j);
    float inv = 1.0f / lj;
    int s = y64A * 64 + w * 16 + g * 4 + j;
    float* op = out + ((size_t)(bb * NS + s)) * NFE + h * NDH;
#pragma unroll
    for (int nf = 0; nf < 8; ++nf) op[nf * 16 + c] = accA[nf][j] * inv;
  }
#pragma unroll
  for (int j = 0; j < 4; ++j) {
    float lj = __shfl(lB, (l & 48) + g * 4 + j);
    float inv = 1.0f / lj;
    int s = y64B * 64 + w * 16 + g * 4 + j;
    float* op = out + ((size_t)(bb * NS + s)) * NFE + h * NDH;
#pragma unroll
    for (int nf = 0; nf < 8; ++nf) op[nf * 16 + c] = accB[nf][j] * inv;
  }
#undef STAGE
#undef TILEBODY
}

extern "C" void kernel_launch(void* const* d_in, const int* in_sizes, int n_in,
                              void* d_out, int out_size, void* d_ws, size_t ws_size,
                              hipStream_t stream) {
  const float* in_q = (const float*)d_in[0];
  const float* Wq = (const float*)d_in[1];
  const float* bq = (const float*)d_in[2];
  const float* Wk = (const float*)d_in[3];
  const float* bk = (const float*)d_in[4];
  const float* Wv = (const float*)d_in[5];
  const float* bv = (const float*)d_in[6];
  // d_in[7] = mask (tril causal, hard-coded), d_in[8] = offset
  const int* offp = (const int*)d_in[8];
  float* out = (float*)d_out;

  char* ws = (char*)d_ws;
  const size_t SZ_AQ = (size_t)4096 * 2048 * 2;        // 16 MB
  const size_t SZ_WT = (size_t)3 * 2048 * 2048 * 2;    // 24 MB
  const size_t SZ_TAB = (size_t)2048 * 64 * 4;         // 512 KB
  const size_t SZ_QKV = (size_t)32 * 2048 * 128 * 2;   // 16 MB each
  uint16_t* Aq = (uint16_t*)(ws);
  uint16_t* Wt = (uint16_t*)(ws + SZ_AQ);
  float* cosT = (float*)(ws + SZ_AQ + SZ_WT);
  float* sinT = (float*)(ws + SZ_AQ + SZ_WT + SZ_TAB);
  uint16_t* qws = (uint16_t*)(ws + SZ_AQ + SZ_WT + 2 * SZ_TAB);
  uint16_t* kws = (uint16_t*)(ws + SZ_AQ + SZ_WT + 2 * SZ_TAB + SZ_QKV);
  uint16_t* vtws = (uint16_t*)(ws + SZ_AQ + SZ_WT + 2 * SZ_TAB + 2 * SZ_QKV);

  k_prep<<<11776, 256, 0, stream>>>(in_q, Aq, cosT, sinT, offp, Wq, Wk, Wv, Wt);
  k_gemm_qkv<<<dim3(32, 48), 256, 0, stream>>>(Aq, Wt, bq, bk, bv, cosT, sinT, qws, kws, vtws);
  k_attn<<<dim3(32, 16), 256, 0, stream>>>(qws, kws, vtws, out);
}